// Round 5
// baseline (426.930 us; speedup 1.0000x reference)
//
#include <hip/hip_runtime.h>
#include <hip/hip_bf16.h>
#include <math.h>

#define NN 8192
#define DD 256
#define RR 32
#define KH 4
#define PP 128      // KH*RR
#define CAP 128     // max neighbors per row (mean ~34)
#define NSTASH 64   // neighbors stashed in LDS (P(nn>64) ~ 0; graceful fallback)
#define ETA 0.5f
#define SCALE 0.17677669529663687f  // 1/sqrt(32)

// ======== K1 fused: A-scan/CSR (blk 0..8191) | Z-GEMM (8192..8447) | orth (8448..8457) ====
__global__ __launch_bounds__(256) void fused1(const float* __restrict__ A,
                                              const float* __restrict__ H,
                                              const float* __restrict__ U,
                                              int* __restrict__ cols,
                                              int* __restrict__ nnzArr,
                                              float* __restrict__ dinv,
                                              float* __restrict__ B2,
                                              float* __restrict__ Z,
                                              float* __restrict__ orth_part,
                                              unsigned* __restrict__ counter) {
  __shared__ float smem[5152];   // 20.6 KB union (zgemm tiles / small scratch)
  int tid = threadIdx.x;
  int bx = blockIdx.x;
  int lane = tid & 63, wv = tid >> 6;

  if (bx >= NN + 256) {
    // ---- orth branch: one (k<=l) head pair per block; reads U directly ----
    int bid = bx - NN - 256;
    int b = bid, k = 0;
    while (b >= (KH - k)) { b -= (KH - k); k++; }
    int l = k + b;
    float* redo = smem;
    const float* uk = U + (size_t)k * DD * RR;
    const float* ul = U + (size_t)l * DD * RR;
    float acc = 0.f;
#pragma unroll
    for (int q = 0; q < 4; ++q) {
      int e = tid * 4 + q;
      int r = e >> 5, s2 = e & 31;
      float g = 0.f;
      for (int d = 0; d < DD; ++d) g += uk[d * RR + r] * ul[d * RR + s2];
      if (k == l) {
        float c3 = g - (r == s2 ? 1.f : 0.f);
        acc += c3 * c3;
      } else {
        acc += g * g;
      }
    }
    redo[tid] = acc;
    __syncthreads();
    for (int off = 128; off > 0; off >>= 1) {
      if (tid < off) redo[tid] += redo[tid + off];
      __syncthreads();
    }
    if (tid == 0) orth_part[bid] = redo[0];
    return;
  }
  if (bx >= NN) {
    // ---- Z-GEMM branch: Z = H @ B1 (B1 read direct from U) ----
    if (bx == NN && tid == 0) *counter = 0u;   // reset K4's last-block counter each launch
    float* As = smem;            // [32][33]
    float* Bs = smem + 1056;     // [32][128]
    int r0 = (bx - NN) * 32;
    int tx = tid & 15, ty = tid >> 4;
    int cx = tx * 8, ry = ty * 2;
    float acc[2][8];
#pragma unroll
    for (int i = 0; i < 2; ++i)
#pragma unroll
      for (int j = 0; j < 8; ++j) acc[i][j] = 0.f;

    for (int k0 = 0; k0 < DD; k0 += 32) {
      {
        int r = tid >> 3;
        int kc = (tid & 7) * 4;
        float4 x = *(const float4*)(H + (size_t)(r0 + r) * DD + k0 + kc);
        As[(kc + 0) * 33 + r] = x.x; As[(kc + 1) * 33 + r] = x.y;
        As[(kc + 2) * 33 + r] = x.z; As[(kc + 3) * 33 + r] = x.w;
      }
#pragma unroll
      for (int q = 0; q < 4; ++q) {
        int f = tid + 256 * q;
        int kk = f >> 5, pc = (f & 31) * 4;
        *(float4*)(&Bs[kk * 128 + pc]) =
            *(const float4*)(U + (size_t)(pc >> 5) * DD * RR + (size_t)(k0 + kk) * RR + (pc & 31));
      }
      __syncthreads();
#pragma unroll
      for (int kk = 0; kk < 32; ++kk) {
        float av[2];
        av[0] = As[kk * 33 + ry]; av[1] = As[kk * 33 + ry + 1];
        float bv[8];
        *(float4*)(bv) = *(const float4*)(&Bs[kk * 128 + cx]);
        *(float4*)(bv + 4) = *(const float4*)(&Bs[kk * 128 + cx + 4]);
#pragma unroll
        for (int i = 0; i < 2; ++i)
#pragma unroll
          for (int j = 0; j < 8; ++j) acc[i][j] += av[i] * bv[j];
      }
      __syncthreads();
    }
#pragma unroll
    for (int i = 0; i < 2; ++i) {
      *(float4*)(Z + (size_t)(r0 + ry + i) * PP + cx) =
          make_float4(acc[i][0], acc[i][1], acc[i][2], acc[i][3]);
      *(float4*)(Z + (size_t)(r0 + ry + i) * PP + cx + 4) =
          make_float4(acc[i][4], acc[i][5], acc[i][6], acc[i][7]);
    }
    return;
  }
  // ---- CSR branch: one A row per block; blocks <128 also transpose U into B2 ----
  int row = bx;
  if (row < 128) {
    int idx = row * 256 + tid;   // B2[p][d] = U[k][d][r]
    int k = idx / (DD * RR);
    int rem = idx % (DD * RR);
    int d = rem / RR;
    int r = rem % RR;
    B2[(k * RR + r) * DD + d] = U[idx];
  }
  const float* a = A + (size_t)row * NN;
  float4 v[8];
  int cnt = 0;
#pragma unroll
  for (int c = 0; c < 8; ++c) {
    v[c] = *(const float4*)(a + tid * 4 + c * 1024);
    cnt += (v[c].x != 0.f) + (v[c].y != 0.f) + (v[c].z != 0.f) + (v[c].w != 0.f);
  }
  int incl = cnt;
#pragma unroll
  for (int off = 1; off < 64; off <<= 1) {
    int t = __shfl_up(incl, off);
    if (lane >= off) incl += t;
  }
  __shared__ int wsum[4];
  if (lane == 63) wsum[wv] = incl;
  __syncthreads();
  int base = 0;
#pragma unroll
  for (int w = 0; w < 4; ++w) if (w < wv) base += wsum[w];
  int o = base + incl - cnt;  // exclusive prefix
#pragma unroll
  for (int c = 0; c < 8; ++c) {
    int col = tid * 4 + c * 1024;
    float4 x = v[c];
    if (x.x != 0.f) { if (o < CAP) cols[(size_t)row * CAP + o] = col + 0; o++; }
    if (x.y != 0.f) { if (o < CAP) cols[(size_t)row * CAP + o] = col + 1; o++; }
    if (x.z != 0.f) { if (o < CAP) cols[(size_t)row * CAP + o] = col + 2; o++; }
    if (x.w != 0.f) { if (o < CAP) cols[(size_t)row * CAP + o] = col + 3; o++; }
  }
  if (tid == 0) {
    int total = wsum[0] + wsum[1] + wsum[2] + wsum[3];
    nnzArr[row] = total < CAP ? total : CAP;
    dinv[row] = 1.0f / sqrtf((float)total);
  }
}

// ======== K2: per-row sparse attention + S-gather (shares one CSR load) ====================
__global__ __launch_bounds__(256) void attn_s(const float* __restrict__ Z,
                                              const float* __restrict__ H,
                                              const int* __restrict__ cols,
                                              const int* __restrict__ nnzArr,
                                              const float* __restrict__ dinv,
                                              float* __restrict__ aggZ,
                                              float* __restrict__ S) {
  int row = blockIdx.x;
  int tid = threadIdx.x;
  int lane = tid & 63, wv = tid >> 6;
  __shared__ int scols[CAP];
  __shared__ float sdinv[CAP];
  __shared__ float zi[PP];
  __shared__ float zz[NSTASH][PP + 1];   // 33 KB
  __shared__ float ar[1040];             // union: sred[4][260] | alpha[4][128]+red[256]
  int nn = nnzArr[row];
  // phase 1: CSR row + own Z
  if (tid < nn) {
    int c = cols[(size_t)row * CAP + tid];
    scols[tid] = c;
    sdinv[tid] = dinv[c];
  }
  if (tid < PP) zi[tid] = Z[(size_t)row * PP + tid];
  __syncthreads();

  // phase 2: stash neighbor Z rows (coalesced) + S-gather partials
  int ns = nn < NSTASH ? nn : NSTASH;
  for (int j = wv; j < ns; j += 4) {
    const float* zj = Z + (size_t)scols[j] * PP;
    float2 x = *(const float2*)(zj + lane * 2);
    zz[j][lane * 2] = x.x;
    zz[j][lane * 2 + 1] = x.y;
  }
  {
    float4 acc = make_float4(0.f, 0.f, 0.f, 0.f);
    for (int jj = wv; jj < nn; jj += 4) {
      float4 x = *(const float4*)(H + (size_t)scols[jj] * DD + lane * 4);
      float w = sdinv[jj];
      acc.x += w * x.x; acc.y += w * x.y; acc.z += w * x.z; acc.w += w * x.w;
    }
    *(float4*)(&ar[wv * 260 + lane * 4]) = acc;
  }
  __syncthreads();

  // phase 3a: S combine (reads sred region of ar)
  float sComb = ar[0 * 260 + tid] + ar[1 * 260 + tid] + ar[2 * 260 + tid] + ar[3 * 260 + tid];
  S[(size_t)row * DD + tid] = sComb;
  __syncthreads();   // sred dead; ar becomes alpha/red

  // phase 3b: scores + wave-parallel softmax (wave wv = head wv)
  {
    int k = wv;
    float s0 = -1e30f, s1 = -1e30f;
    if (lane < nn) {
      const float* zs = &zz[lane][k * RR];
      float acc = 0.f;
#pragma unroll
      for (int r = 0; r < RR; r += 4) {
        float4 a = *(const float4*)(zi + k * RR + r);
        acc += a.x * zs[r] + a.y * zs[r + 1] + a.z * zs[r + 2] + a.w * zs[r + 3];
      }
      s0 = acc * SCALE;
    }
    int j1 = lane + 64;
    if (j1 < nn) {
      const float* zj = Z + (size_t)scols[j1] * PP + k * RR;
      float acc = 0.f;
#pragma unroll
      for (int r = 0; r < RR; r += 4) {
        float4 a = *(const float4*)(zi + k * RR + r);
        float4 b = *(const float4*)(zj + r);
        acc += a.x * b.x + a.y * b.y + a.z * b.z + a.w * b.w;
      }
      s1 = acc * SCALE;
    }
    float m = fmaxf(s0, s1);
#pragma unroll
    for (int off = 32; off > 0; off >>= 1) m = fmaxf(m, __shfl_xor(m, off));
    float e0 = (lane < nn) ? expf(s0 - m) : 0.f;
    float e1 = (j1 < nn) ? expf(s1 - m) : 0.f;
    float s = e0 + e1;
#pragma unroll
    for (int off = 32; off > 0; off >>= 1) s += __shfl_xor(s, off);
    float inv = 1.0f / s;
    if (lane < nn) ar[k * CAP + lane] = e0 * inv;          // alpha[k][lane]
    if (j1 < nn) ar[k * CAP + j1] = e1 * inv;
  }
  __syncthreads();

  // phase 4: aggZ[row][p] = sum_j alpha*zz, chain split across 2 halves
  {
    int p = tid & 127, hf = tid >> 7;
    float acc = 0.f;
    for (int jj = hf; jj < nn; jj += 2) {
      float zv = (jj < NSTASH) ? zz[jj][p] : Z[(size_t)scols[jj] * PP + p];
      acc += ar[(p >> 5) * CAP + jj] * zv;
    }
    ar[512 + tid] = acc;   // red[tid]  (alpha occupies ar[0..512))
  }
  __syncthreads();
  if (tid < PP) aggZ[(size_t)row * PP + tid] = ar[512 + tid] + ar[512 + tid + 128];
}

// ======== K3: epilogue GEMM + Laplacian + soft-threshold ==================================
__global__ __launch_bounds__(256) void egemm(const float* __restrict__ A,   // aggZ [N][128]
                                             const float* __restrict__ B,   // B2 [128][256]
                                             const float* __restrict__ Hm,
                                             const float* __restrict__ S,
                                             const float* __restrict__ dinv,
                                             const float* __restrict__ thr,
                                             const float* __restrict__ lambda_p,
                                             float* __restrict__ out) {
  __shared__ float As[32][33];
  __shared__ float Bs[32][128];
  int tid = threadIdx.x;
  int r0 = blockIdx.x * 32;
  int c0 = blockIdx.y * 128;
  int tx = tid & 15, ty = tid >> 4;
  int cx = tx * 8, ry = ty * 2;
  float acc[2][8];
#pragma unroll
  for (int i = 0; i < 2; ++i)
#pragma unroll
    for (int j = 0; j < 8; ++j) acc[i][j] = 0.f;

  for (int k0 = 0; k0 < PP; k0 += 32) {
    {
      int r = tid >> 3;
      int kc = (tid & 7) * 4;
      float4 x = *(const float4*)(A + (size_t)(r0 + r) * PP + k0 + kc);
      As[kc + 0][r] = x.x; As[kc + 1][r] = x.y; As[kc + 2][r] = x.z; As[kc + 3][r] = x.w;
    }
#pragma unroll
    for (int q = 0; q < 4; ++q) {
      int f = tid + 256 * q;
      int kk = f >> 5, pc = (f & 31) * 4;
      *(float4*)(&Bs[kk][pc]) = *(const float4*)(B + (size_t)(k0 + kk) * DD + c0 + pc);
    }
    __syncthreads();
#pragma unroll
    for (int kk = 0; kk < 32; ++kk) {
      float av[2];
      av[0] = As[kk][ry]; av[1] = As[kk][ry + 1];
      float bv[8];
      *(float4*)(bv) = *(const float4*)(&Bs[kk][cx]);
      *(float4*)(bv + 4) = *(const float4*)(&Bs[kk][cx + 4]);
#pragma unroll
      for (int i = 0; i < 2; ++i)
#pragma unroll
        for (int j = 0; j < 8; ++j) acc[i][j] += av[i] * bv[j];
    }
    __syncthreads();
  }
  float lam = lambda_p[0];
  int gc = c0 + cx;
  float4 t0 = *(const float4*)(thr + gc);
  float4 t1 = *(const float4*)(thr + gc + 4);
#pragma unroll
  for (int i = 0; i < 2; ++i) {
    int gr = r0 + ry + i;
    float dv = dinv[gr];
    float4 h0 = *(const float4*)(Hm + (size_t)gr * DD + gc);
    float4 h1 = *(const float4*)(Hm + (size_t)gr * DD + gc + 4);
    float4 s0 = *(const float4*)(S + (size_t)gr * DD + gc);
    float4 s1 = *(const float4*)(S + (size_t)gr * DD + gc + 4);
    float hv[8] = {h0.x, h0.y, h0.z, h0.w, h1.x, h1.y, h1.z, h1.w};
    float sv[8] = {s0.x, s0.y, s0.z, s0.w, s1.x, s1.y, s1.z, s1.w};
    float tv[8] = {t0.x, t0.y, t0.z, t0.w, t1.x, t1.y, t1.z, t1.w};
    float ov[8];
#pragma unroll
    for (int j = 0; j < 8; ++j) {
      float val = hv[j] + ETA * acc[i][j] - ETA * lam * (hv[j] - dv * sv[j]);
      float av = fabsf(val) - tv[j];
      ov[j] = (av > 0.f) ? copysignf(av, val) : 0.f;
    }
    *(float4*)(out + (size_t)gr * DD + gc) = make_float4(ov[0], ov[1], ov[2], ov[3]);
    *(float4*)(out + (size_t)gr * DD + gc + 4) = make_float4(ov[4], ov[5], ov[6], ov[7]);
  }
}

// ======== K4: lap_smooth rows + last-block deterministic finalize ==========================
__global__ __launch_bounds__(256) void lap_fin(const float* __restrict__ Hout,
                                               const int* __restrict__ cols,
                                               const int* __restrict__ nnzArr,
                                               const float* __restrict__ dinv,
                                               float* __restrict__ part,
                                               const float* __restrict__ orth_part,
                                               unsigned* __restrict__ counter,
                                               float* __restrict__ out) {
  int row = blockIdx.x;
  int tid = threadIdx.x;
  int lane = tid & 63, wv = tid >> 6;
  __shared__ int scols[CAP];
  __shared__ float sdinv[CAP];
  __shared__ float sred[4][260];
  __shared__ double dred[256];
  __shared__ unsigned sold;
  int nn = nnzArr[row];
  if (tid < nn) {
    int c = cols[(size_t)row * CAP + tid];
    scols[tid] = c;
    sdinv[tid] = dinv[c];
  }
  __syncthreads();
  float4 acc = make_float4(0.f, 0.f, 0.f, 0.f);
  for (int jj = wv; jj < nn; jj += 4) {
    float4 x = *(const float4*)(Hout + (size_t)scols[jj] * DD + lane * 4);
    float w = sdinv[jj];
    acc.x += w * x.x; acc.y += w * x.y; acc.z += w * x.z; acc.w += w * x.w;
  }
  *(float4*)(&sred[wv][lane * 4]) = acc;
  __syncthreads();
  if (wv == 0) {
    float4 s4;
    s4.x = sred[0][lane * 4 + 0] + sred[1][lane * 4 + 0] + sred[2][lane * 4 + 0] + sred[3][lane * 4 + 0];
    s4.y = sred[0][lane * 4 + 1] + sred[1][lane * 4 + 1] + sred[2][lane * 4 + 1] + sred[3][lane * 4 + 1];
    s4.z = sred[0][lane * 4 + 2] + sred[1][lane * 4 + 2] + sred[2][lane * 4 + 2] + sred[3][lane * 4 + 2];
    s4.w = sred[0][lane * 4 + 3] + sred[1][lane * 4 + 3] + sred[2][lane * 4 + 3] + sred[3][lane * 4 + 3];
    float4 h4 = *(const float4*)(Hout + (size_t)row * DD + lane * 4);
    float dvr = dinv[row];
    float val = h4.x * (h4.x - dvr * s4.x) + h4.y * (h4.y - dvr * s4.y) +
                h4.z * (h4.z - dvr * s4.z) + h4.w * (h4.w - dvr * s4.w);
#pragma unroll
    for (int off = 32; off > 0; off >>= 1) val += __shfl_xor(val, off);
    if (lane == 0) {
      __hip_atomic_store(&part[row], val, __ATOMIC_RELAXED, __HIP_MEMORY_SCOPE_AGENT);
      __threadfence();
      sold = atomicAdd(counter, 1u);
    }
  }
  __syncthreads();
  if (sold == NN - 1) {
    // last block: deterministic fixed-order final reduction
    double s = 0.0;
    for (int i = tid; i < NN; i += 256)
      s += (double)__hip_atomic_load(&part[i], __ATOMIC_RELAXED, __HIP_MEMORY_SCOPE_AGENT);
    dred[tid] = s;
    __syncthreads();
    for (int off = 128; off > 0; off >>= 1) {
      if (tid < off) dred[tid] += dred[tid + off];
      __syncthreads();
    }
    if (tid == 0) {
      double o = 0.0;
      for (int i = 0; i < 10; ++i) o += (double)orth_part[i];
      out[(size_t)NN * DD] = (float)o;
      out[(size_t)NN * DD + 1] = (float)dred[0];
    }
  }
}

extern "C" void kernel_launch(void* const* d_in, const int* in_sizes, int n_in,
                              void* d_out, int out_size, void* d_ws, size_t ws_size,
                              hipStream_t stream) {
  const float* H = (const float*)d_in[0];
  const float* A = (const float*)d_in[1];
  // d_in[2] (dense L) intentionally unused: L reconstructed exactly from A.
  const float* U = (const float*)d_in[3];
  const float* lambda_p = (const float*)d_in[4];
  const float* thr = (const float*)d_in[5];
  float* out = (float*)d_out;

  char* w = (char*)d_ws;
  float* B2 = (float*)w;        w += (size_t)PP * DD * 4;       // 128 KB
  int* cols = (int*)w;          w += (size_t)NN * CAP * 4;      // 4 MB
  int* nnzArr = (int*)w;        w += (size_t)NN * 4;
  float* dinv = (float*)w;      w += (size_t)NN * 4;
  float* Z = (float*)w;         w += (size_t)NN * PP * 4;       // 4 MB
  float* aggZ = (float*)w;      w += (size_t)NN * PP * 4;       // 4 MB
  float* S = (float*)w;         w += (size_t)NN * DD * 4;       // 8 MB
  float* lap_part = (float*)w;  w += (size_t)NN * 4;
  float* orth_part = (float*)w; w += 64;
  unsigned* counter = (unsigned*)w; w += 64;

  fused1<<<dim3(NN + 256 + 10), dim3(256), 0, stream>>>(A, H, U, cols, nnzArr, dinv,
                                                        B2, Z, orth_part, counter);
  attn_s<<<dim3(NN), dim3(256), 0, stream>>>(Z, H, cols, nnzArr, dinv, aggZ, S);
  egemm<<<dim3(NN / 32, 2), dim3(256), 0, stream>>>(aggZ, B2, H, S, dinv, thr, lambda_p, out);
  lap_fin<<<dim3(NN), dim3(256), 0, stream>>>(out, cols, nnzArr, dinv, lap_part,
                                              orth_part, counter, out);
}

// Round 6
// 203.672 us; speedup vs baseline: 2.0962x; 2.0962x over previous
//
#include <hip/hip_runtime.h>
#include <hip/hip_bf16.h>
#include <math.h>

#define NN 8192
#define DD 256
#define RR 32
#define KH 4
#define PP 128      // KH*RR
#define CAP 128     // max neighbors per row (mean ~34)
#define NSTASH 64   // neighbors stashed in LDS (P(nn>64) ~ 0; graceful fallback)
#define ETA 0.5f
#define SCALE 0.17677669529663687f  // 1/sqrt(32)
#define NGB 266     // non-CSR blocks in fused1: 256 zgemm + 10 orth

// ======== K1 fused: Z-GEMM (blk 0..255) | orth (256..265) | A-scan/CSR (266..8457) ========
// GEMM/orth first: they dispatch immediately and hide under the BW-bound A-scan.
__global__ __launch_bounds__(256) void fused1(const float* __restrict__ A,
                                              const float* __restrict__ H,
                                              const float* __restrict__ U,
                                              int* __restrict__ cols,
                                              int* __restrict__ nnzArr,
                                              float* __restrict__ dinv,
                                              float* __restrict__ B2,
                                              float* __restrict__ Z,
                                              float* __restrict__ orth_part) {
  __shared__ float smem[5152];   // 20.6 KB union (zgemm tiles / reduction scratch)
  int tid = threadIdx.x;
  int bx = blockIdx.x;
  int lane = tid & 63, wv = tid >> 6;

  if (bx < 256) {
    // ---- Z-GEMM branch: Z = H @ B1 (B1 read direct from U) ----
    float* As = smem;            // [32][33]
    float* Bs = smem + 1056;     // [32][128]
    int r0 = bx * 32;
    int tx = tid & 15, ty = tid >> 4;
    int cx = tx * 8, ry = ty * 2;
    float acc[2][8];
#pragma unroll
    for (int i = 0; i < 2; ++i)
#pragma unroll
      for (int j = 0; j < 8; ++j) acc[i][j] = 0.f;

    for (int k0 = 0; k0 < DD; k0 += 32) {
      {
        int r = tid >> 3;
        int kc = (tid & 7) * 4;
        float4 x = *(const float4*)(H + (size_t)(r0 + r) * DD + k0 + kc);
        As[(kc + 0) * 33 + r] = x.x; As[(kc + 1) * 33 + r] = x.y;
        As[(kc + 2) * 33 + r] = x.z; As[(kc + 3) * 33 + r] = x.w;
      }
#pragma unroll
      for (int q = 0; q < 4; ++q) {
        int f = tid + 256 * q;
        int kk = f >> 5, pc = (f & 31) * 4;
        *(float4*)(&Bs[kk * 128 + pc]) =
            *(const float4*)(U + (size_t)(pc >> 5) * DD * RR + (size_t)(k0 + kk) * RR + (pc & 31));
      }
      __syncthreads();
#pragma unroll
      for (int kk = 0; kk < 32; ++kk) {
        float av[2];
        av[0] = As[kk * 33 + ry]; av[1] = As[kk * 33 + ry + 1];
        float bv[8];
        *(float4*)(bv) = *(const float4*)(&Bs[kk * 128 + cx]);
        *(float4*)(bv + 4) = *(const float4*)(&Bs[kk * 128 + cx + 4]);
#pragma unroll
        for (int i = 0; i < 2; ++i)
#pragma unroll
          for (int j = 0; j < 8; ++j) acc[i][j] += av[i] * bv[j];
      }
      __syncthreads();
    }
#pragma unroll
    for (int i = 0; i < 2; ++i) {
      *(float4*)(Z + (size_t)(r0 + ry + i) * PP + cx) =
          make_float4(acc[i][0], acc[i][1], acc[i][2], acc[i][3]);
      *(float4*)(Z + (size_t)(r0 + ry + i) * PP + cx + 4) =
          make_float4(acc[i][4], acc[i][5], acc[i][6], acc[i][7]);
    }
    return;
  }
  if (bx < NGB) {
    // ---- orth branch: one (k<=l) head pair per block; reads U directly ----
    int bid = bx - 256;
    int b = bid, k = 0;
    while (b >= (KH - k)) { b -= (KH - k); k++; }
    int l = k + b;
    float* redo = smem;
    const float* uk = U + (size_t)k * DD * RR;
    const float* ul = U + (size_t)l * DD * RR;
    float acc = 0.f;
#pragma unroll
    for (int q = 0; q < 4; ++q) {
      int e = tid * 4 + q;
      int r = e >> 5, s2 = e & 31;
      float g = 0.f;
      for (int d = 0; d < DD; ++d) g += uk[d * RR + r] * ul[d * RR + s2];
      if (k == l) {
        float c3 = g - (r == s2 ? 1.f : 0.f);
        acc += c3 * c3;
      } else {
        acc += g * g;
      }
    }
    redo[tid] = acc;
    __syncthreads();
    for (int off = 128; off > 0; off >>= 1) {
      if (tid < off) redo[tid] += redo[tid + off];
      __syncthreads();
    }
    if (tid == 0) orth_part[bid] = redo[0];
    return;
  }
  // ---- CSR branch: one A row per block; first 128 also transpose U into B2 ----
  int row = bx - NGB;
  if (row < 128) {
    int idx = row * 256 + tid;   // B2[p][d] = U[k][d][r]
    int k = idx / (DD * RR);
    int rem = idx % (DD * RR);
    int d = rem / RR;
    int r = rem % RR;
    B2[(k * RR + r) * DD + d] = U[idx];
  }
  const float* a = A + (size_t)row * NN;
  float4 v[8];
  int cnt = 0;
#pragma unroll
  for (int c = 0; c < 8; ++c) {
    v[c] = *(const float4*)(a + tid * 4 + c * 1024);
    cnt += (v[c].x != 0.f) + (v[c].y != 0.f) + (v[c].z != 0.f) + (v[c].w != 0.f);
  }
  int incl = cnt;
#pragma unroll
  for (int off = 1; off < 64; off <<= 1) {
    int t = __shfl_up(incl, off);
    if (lane >= off) incl += t;
  }
  __shared__ int wsum[4];
  if (lane == 63) wsum[wv] = incl;
  __syncthreads();
  int base = 0;
#pragma unroll
  for (int w = 0; w < 4; ++w) if (w < wv) base += wsum[w];
  int o = base + incl - cnt;  // exclusive prefix
#pragma unroll
  for (int c = 0; c < 8; ++c) {
    int col = tid * 4 + c * 1024;
    float4 x = v[c];
    if (x.x != 0.f) { if (o < CAP) cols[(size_t)row * CAP + o] = col + 0; o++; }
    if (x.y != 0.f) { if (o < CAP) cols[(size_t)row * CAP + o] = col + 1; o++; }
    if (x.z != 0.f) { if (o < CAP) cols[(size_t)row * CAP + o] = col + 2; o++; }
    if (x.w != 0.f) { if (o < CAP) cols[(size_t)row * CAP + o] = col + 3; o++; }
  }
  if (tid == 0) {
    int total = wsum[0] + wsum[1] + wsum[2] + wsum[3];
    nnzArr[row] = total < CAP ? total : CAP;
    dinv[row] = 1.0f / sqrtf((float)total);
  }
}

// ======== K2: per-row sparse attention + S-gather (shares one CSR load) ====================
__global__ __launch_bounds__(256) void attn_s(const float* __restrict__ Z,
                                              const float* __restrict__ H,
                                              const int* __restrict__ cols,
                                              const int* __restrict__ nnzArr,
                                              const float* __restrict__ dinv,
                                              float* __restrict__ aggZ,
                                              float* __restrict__ S) {
  int row = blockIdx.x;
  int tid = threadIdx.x;
  int lane = tid & 63, wv = tid >> 6;
  __shared__ int scols[CAP];
  __shared__ float sdinv[CAP];
  __shared__ float zi[PP];
  __shared__ float zz[NSTASH][PP + 1];   // 33 KB
  __shared__ float ar[1040];             // union: sred[4][260] | alpha[4][128]+red[256]
  int nn = nnzArr[row];
  // phase 1: CSR row + own Z
  if (tid < nn) {
    int c = cols[(size_t)row * CAP + tid];
    scols[tid] = c;
    sdinv[tid] = dinv[c];
  }
  if (tid < PP) zi[tid] = Z[(size_t)row * PP + tid];
  __syncthreads();

  // phase 2: stash neighbor Z rows (coalesced) + S-gather partials
  int ns = nn < NSTASH ? nn : NSTASH;
  for (int j = wv; j < ns; j += 4) {
    const float* zj = Z + (size_t)scols[j] * PP;
    float2 x = *(const float2*)(zj + lane * 2);
    zz[j][lane * 2] = x.x;
    zz[j][lane * 2 + 1] = x.y;
  }
  {
    float4 acc = make_float4(0.f, 0.f, 0.f, 0.f);
    for (int jj = wv; jj < nn; jj += 4) {
      float4 x = *(const float4*)(H + (size_t)scols[jj] * DD + lane * 4);
      float w = sdinv[jj];
      acc.x += w * x.x; acc.y += w * x.y; acc.z += w * x.z; acc.w += w * x.w;
    }
    *(float4*)(&ar[wv * 260 + lane * 4]) = acc;
  }
  __syncthreads();

  // phase 3a: S combine (reads sred region of ar)
  float sComb = ar[0 * 260 + tid] + ar[1 * 260 + tid] + ar[2 * 260 + tid] + ar[3 * 260 + tid];
  S[(size_t)row * DD + tid] = sComb;
  __syncthreads();   // sred dead; ar becomes alpha/red

  // phase 3b: scores + wave-parallel softmax (wave wv = head wv)
  {
    int k = wv;
    float s0 = -1e30f, s1 = -1e30f;
    if (lane < nn) {
      const float* zs = &zz[lane][k * RR];
      float acc = 0.f;
#pragma unroll
      for (int r = 0; r < RR; r += 4) {
        float4 a = *(const float4*)(zi + k * RR + r);
        acc += a.x * zs[r] + a.y * zs[r + 1] + a.z * zs[r + 2] + a.w * zs[r + 3];
      }
      s0 = acc * SCALE;
    }
    int j1 = lane + 64;
    if (j1 < nn) {
      const float* zj = Z + (size_t)scols[j1] * PP + k * RR;
      float acc = 0.f;
#pragma unroll
      for (int r = 0; r < RR; r += 4) {
        float4 a = *(const float4*)(zi + k * RR + r);
        float4 b = *(const float4*)(zj + r);
        acc += a.x * b.x + a.y * b.y + a.z * b.z + a.w * b.w;
      }
      s1 = acc * SCALE;
    }
    float m = fmaxf(s0, s1);
#pragma unroll
    for (int off = 32; off > 0; off >>= 1) m = fmaxf(m, __shfl_xor(m, off));
    float e0 = (lane < nn) ? expf(s0 - m) : 0.f;
    float e1 = (j1 < nn) ? expf(s1 - m) : 0.f;
    float s = e0 + e1;
#pragma unroll
    for (int off = 32; off > 0; off >>= 1) s += __shfl_xor(s, off);
    float inv = 1.0f / s;
    if (lane < nn) ar[k * CAP + lane] = e0 * inv;          // alpha[k][lane]
    if (j1 < nn) ar[k * CAP + j1] = e1 * inv;
  }
  __syncthreads();

  // phase 4: aggZ[row][p] = sum_j alpha*zz, chain split across 2 halves
  {
    int p = tid & 127, hf = tid >> 7;
    float acc = 0.f;
    for (int jj = hf; jj < nn; jj += 2) {
      float zv = (jj < NSTASH) ? zz[jj][p] : Z[(size_t)scols[jj] * PP + p];
      acc += ar[(p >> 5) * CAP + jj] * zv;
    }
    ar[512 + tid] = acc;   // red[tid]  (alpha occupies ar[0..512))
  }
  __syncthreads();
  if (tid < PP) aggZ[(size_t)row * PP + tid] = ar[512 + tid] + ar[512 + tid + 128];
}

// ======== K3: epilogue GEMM + Laplacian + soft-threshold ==================================
__global__ __launch_bounds__(256) void egemm(const float* __restrict__ A,   // aggZ [N][128]
                                             const float* __restrict__ B,   // B2 [128][256]
                                             const float* __restrict__ Hm,
                                             const float* __restrict__ S,
                                             const float* __restrict__ dinv,
                                             const float* __restrict__ thr,
                                             const float* __restrict__ lambda_p,
                                             float* __restrict__ out) {
  __shared__ float As[32][33];
  __shared__ float Bs[32][128];
  int tid = threadIdx.x;
  int r0 = blockIdx.x * 32;
  int c0 = blockIdx.y * 128;
  int tx = tid & 15, ty = tid >> 4;
  int cx = tx * 8, ry = ty * 2;
  float acc[2][8];
#pragma unroll
  for (int i = 0; i < 2; ++i)
#pragma unroll
    for (int j = 0; j < 8; ++j) acc[i][j] = 0.f;

  for (int k0 = 0; k0 < PP; k0 += 32) {
    {
      int r = tid >> 3;
      int kc = (tid & 7) * 4;
      float4 x = *(const float4*)(A + (size_t)(r0 + r) * PP + k0 + kc);
      As[kc + 0][r] = x.x; As[kc + 1][r] = x.y; As[kc + 2][r] = x.z; As[kc + 3][r] = x.w;
    }
#pragma unroll
    for (int q = 0; q < 4; ++q) {
      int f = tid + 256 * q;
      int kk = f >> 5, pc = (f & 31) * 4;
      *(float4*)(&Bs[kk][pc]) = *(const float4*)(B + (size_t)(k0 + kk) * DD + c0 + pc);
    }
    __syncthreads();
#pragma unroll
    for (int kk = 0; kk < 32; ++kk) {
      float av[2];
      av[0] = As[kk][ry]; av[1] = As[kk][ry + 1];
      float bv[8];
      *(float4*)(bv) = *(const float4*)(&Bs[kk][cx]);
      *(float4*)(bv + 4) = *(const float4*)(&Bs[kk][cx + 4]);
#pragma unroll
      for (int i = 0; i < 2; ++i)
#pragma unroll
        for (int j = 0; j < 8; ++j) acc[i][j] += av[i] * bv[j];
    }
    __syncthreads();
  }
  float lam = lambda_p[0];
  int gc = c0 + cx;
  float4 t0 = *(const float4*)(thr + gc);
  float4 t1 = *(const float4*)(thr + gc + 4);
#pragma unroll
  for (int i = 0; i < 2; ++i) {
    int gr = r0 + ry + i;
    float dv = dinv[gr];
    float4 h0 = *(const float4*)(Hm + (size_t)gr * DD + gc);
    float4 h1 = *(const float4*)(Hm + (size_t)gr * DD + gc + 4);
    float4 s0 = *(const float4*)(S + (size_t)gr * DD + gc);
    float4 s1 = *(const float4*)(S + (size_t)gr * DD + gc + 4);
    float hv[8] = {h0.x, h0.y, h0.z, h0.w, h1.x, h1.y, h1.z, h1.w};
    float sv[8] = {s0.x, s0.y, s0.z, s0.w, s1.x, s1.y, s1.z, s1.w};
    float tv[8] = {t0.x, t0.y, t0.z, t0.w, t1.x, t1.y, t1.z, t1.w};
    float ov[8];
#pragma unroll
    for (int j = 0; j < 8; ++j) {
      float val = hv[j] + ETA * acc[i][j] - ETA * lam * (hv[j] - dv * sv[j]);
      float av = fabsf(val) - tv[j];
      ov[j] = (av > 0.f) ? copysignf(av, val) : 0.f;
    }
    *(float4*)(out + (size_t)gr * DD + gc) = make_float4(ov[0], ov[1], ov[2], ov[3]);
    *(float4*)(out + (size_t)gr * DD + gc + 4) = make_float4(ov[4], ov[5], ov[6], ov[7]);
  }
}

// ======== K4: lap_smooth per-row partials (wave-split float4 gather; no fences) ===========
__global__ __launch_bounds__(256) void lap_rows(const float* __restrict__ Hout,
                                                const int* __restrict__ cols,
                                                const int* __restrict__ nnzArr,
                                                const float* __restrict__ dinv,
                                                float* __restrict__ part) {
  int row = blockIdx.x;
  int tid = threadIdx.x;
  int lane = tid & 63, wv = tid >> 6;
  __shared__ int scols[CAP];
  __shared__ float sdinv[CAP];
  __shared__ float sred[4][260];
  int nn = nnzArr[row];
  if (tid < nn) {
    int c = cols[(size_t)row * CAP + tid];
    scols[tid] = c;
    sdinv[tid] = dinv[c];
  }
  __syncthreads();
  float4 acc = make_float4(0.f, 0.f, 0.f, 0.f);
  for (int jj = wv; jj < nn; jj += 4) {
    float4 x = *(const float4*)(Hout + (size_t)scols[jj] * DD + lane * 4);
    float w = sdinv[jj];
    acc.x += w * x.x; acc.y += w * x.y; acc.z += w * x.z; acc.w += w * x.w;
  }
  *(float4*)(&sred[wv][lane * 4]) = acc;
  __syncthreads();
  if (wv == 0) {
    float4 s4;
    s4.x = sred[0][lane * 4 + 0] + sred[1][lane * 4 + 0] + sred[2][lane * 4 + 0] + sred[3][lane * 4 + 0];
    s4.y = sred[0][lane * 4 + 1] + sred[1][lane * 4 + 1] + sred[2][lane * 4 + 1] + sred[3][lane * 4 + 1];
    s4.z = sred[0][lane * 4 + 2] + sred[1][lane * 4 + 2] + sred[2][lane * 4 + 2] + sred[3][lane * 4 + 2];
    s4.w = sred[0][lane * 4 + 3] + sred[1][lane * 4 + 3] + sred[2][lane * 4 + 3] + sred[3][lane * 4 + 3];
    float4 h4 = *(const float4*)(Hout + (size_t)row * DD + lane * 4);
    float dvr = dinv[row];
    float val = h4.x * (h4.x - dvr * s4.x) + h4.y * (h4.y - dvr * s4.y) +
                h4.z * (h4.z - dvr * s4.z) + h4.w * (h4.w - dvr * s4.w);
#pragma unroll
    for (int off = 32; off > 0; off >>= 1) val += __shfl_xor(val, off);
    if (lane == 0) part[row] = val;
  }
}

// ======== K5: deterministic final reduction ==============================================
__global__ __launch_bounds__(256) void finalize(const float* __restrict__ lap_part,
                                                const float* __restrict__ orth_part,
                                                float* __restrict__ out) {
  __shared__ double red[256];
  int tid = threadIdx.x;
  double s = 0.0;
  for (int i = tid; i < NN; i += 256) s += (double)lap_part[i];
  red[tid] = s;
  __syncthreads();
  for (int off = 128; off > 0; off >>= 1) {
    if (tid < off) red[tid] += red[tid + off];
    __syncthreads();
  }
  if (tid == 0) {
    double o = 0.0;
    for (int i = 0; i < 10; ++i) o += (double)orth_part[i];
    out[(size_t)NN * DD] = (float)o;
    out[(size_t)NN * DD + 1] = (float)red[0];
  }
}

extern "C" void kernel_launch(void* const* d_in, const int* in_sizes, int n_in,
                              void* d_out, int out_size, void* d_ws, size_t ws_size,
                              hipStream_t stream) {
  const float* H = (const float*)d_in[0];
  const float* A = (const float*)d_in[1];
  // d_in[2] (dense L) intentionally unused: L reconstructed exactly from A.
  const float* U = (const float*)d_in[3];
  const float* lambda_p = (const float*)d_in[4];
  const float* thr = (const float*)d_in[5];
  float* out = (float*)d_out;

  char* w = (char*)d_ws;
  float* B2 = (float*)w;        w += (size_t)PP * DD * 4;       // 128 KB
  int* cols = (int*)w;          w += (size_t)NN * CAP * 4;      // 4 MB
  int* nnzArr = (int*)w;        w += (size_t)NN * 4;
  float* dinv = (float*)w;      w += (size_t)NN * 4;
  float* Z = (float*)w;         w += (size_t)NN * PP * 4;       // 4 MB
  float* aggZ = (float*)w;      w += (size_t)NN * PP * 4;       // 4 MB
  float* S = (float*)w;         w += (size_t)NN * DD * 4;       // 8 MB
  float* lap_part = (float*)w;  w += (size_t)NN * 4;
  float* orth_part = (float*)w; w += 64;

  fused1<<<dim3(NN + NGB), dim3(256), 0, stream>>>(A, H, U, cols, nnzArr, dinv,
                                                   B2, Z, orth_part);
  attn_s<<<dim3(NN), dim3(256), 0, stream>>>(Z, H, cols, nnzArr, dinv, aggZ, S);
  egemm<<<dim3(NN / 32, 2), dim3(256), 0, stream>>>(aggZ, B2, H, S, dinv, thr, lambda_p, out);
  lap_rows<<<dim3(NN), dim3(256), 0, stream>>>(out, cols, nnzArr, dinv, lap_part);
  finalize<<<dim3(1), dim3(256), 0, stream>>>(lap_part, orth_part, out);
}

// Round 7
// 199.399 us; speedup vs baseline: 2.1411x; 1.0214x over previous
//
#include <hip/hip_runtime.h>
#include <hip/hip_bf16.h>
#include <math.h>

#define NN 8192
#define DD 256
#define RR 32
#define KH 4
#define PP 128      // KH*RR
#define CAP 128     // max neighbors per row (mean ~34)
#define NSTASH 64   // neighbors stashed in LDS (P(nn>64) ~ 0; graceful fallback)
#define ETA 0.5f
#define SCALE 0.17677669529663687f  // 1/sqrt(32)

// ======== K1: Z-GEMM (blk 0..255) | orth (256..265) | B2 transpose (266..393) =============
__global__ __launch_bounds__(256) void zgemm_orth(const float* __restrict__ H,
                                                  const float* __restrict__ U,
                                                  float* __restrict__ B2,
                                                  float* __restrict__ Z,
                                                  float* __restrict__ orth_part) {
  __shared__ float smem[5152];
  int tid = threadIdx.x;
  int bx = blockIdx.x;

  if (bx >= 266) {
    // ---- B2 transpose: B2[p][d] = U[k][d][r] ----
    int idx = (bx - 266) * 256 + tid;   // 0..32767
    int k = idx / (DD * RR);
    int rem = idx % (DD * RR);
    int d = rem / RR;
    int r = rem % RR;
    B2[(k * RR + r) * DD + d] = U[idx];
    return;
  }
  if (bx >= 256) {
    // ---- orth: one (k<=l) head pair per block; reads U directly ----
    int bid = bx - 256;
    int b = bid, k = 0;
    while (b >= (KH - k)) { b -= (KH - k); k++; }
    int l = k + b;
    float* redo = smem;
    const float* uk = U + (size_t)k * DD * RR;
    const float* ul = U + (size_t)l * DD * RR;
    float acc = 0.f;
#pragma unroll
    for (int q = 0; q < 4; ++q) {
      int e = tid * 4 + q;
      int r = e >> 5, s2 = e & 31;
      float g = 0.f;
      for (int d = 0; d < DD; ++d) g += uk[d * RR + r] * ul[d * RR + s2];
      if (k == l) {
        float c3 = g - (r == s2 ? 1.f : 0.f);
        acc += c3 * c3;
      } else {
        acc += g * g;
      }
    }
    redo[tid] = acc;
    __syncthreads();
    for (int off = 128; off > 0; off >>= 1) {
      if (tid < off) redo[tid] += redo[tid + off];
      __syncthreads();
    }
    if (tid == 0) orth_part[bid] = redo[0];
    return;
  }
  // ---- Z-GEMM: Z = H @ B1 (B1 read direct from U) ----
  float* As = smem;            // [32][33]
  float* Bs = smem + 1056;     // [32][128]
  int r0 = bx * 32;
  int tx = tid & 15, ty = tid >> 4;
  int cx = tx * 8, ry = ty * 2;
  float acc[2][8];
#pragma unroll
  for (int i = 0; i < 2; ++i)
#pragma unroll
    for (int j = 0; j < 8; ++j) acc[i][j] = 0.f;

  for (int k0 = 0; k0 < DD; k0 += 32) {
    {
      int r = tid >> 3;
      int kc = (tid & 7) * 4;
      float4 x = *(const float4*)(H + (size_t)(r0 + r) * DD + k0 + kc);
      As[(kc + 0) * 33 + r] = x.x; As[(kc + 1) * 33 + r] = x.y;
      As[(kc + 2) * 33 + r] = x.z; As[(kc + 3) * 33 + r] = x.w;
    }
#pragma unroll
    for (int q = 0; q < 4; ++q) {
      int f = tid + 256 * q;
      int kk = f >> 5, pc = (f & 31) * 4;
      *(float4*)(&Bs[kk * 128 + pc]) =
          *(const float4*)(U + (size_t)(pc >> 5) * DD * RR + (size_t)(k0 + kk) * RR + (pc & 31));
    }
    __syncthreads();
#pragma unroll
    for (int kk = 0; kk < 32; ++kk) {
      float av[2];
      av[0] = As[kk * 33 + ry]; av[1] = As[kk * 33 + ry + 1];
      float bv[8];
      *(float4*)(bv) = *(const float4*)(&Bs[kk * 128 + cx]);
      *(float4*)(bv + 4) = *(const float4*)(&Bs[kk * 128 + cx + 4]);
#pragma unroll
      for (int i = 0; i < 2; ++i)
#pragma unroll
        for (int j = 0; j < 8; ++j) acc[i][j] += av[i] * bv[j];
    }
    __syncthreads();
  }
#pragma unroll
  for (int i = 0; i < 2; ++i) {
    *(float4*)(Z + (size_t)(r0 + ry + i) * PP + cx) =
        make_float4(acc[i][0], acc[i][1], acc[i][2], acc[i][3]);
    *(float4*)(Z + (size_t)(r0 + ry + i) * PP + cx + 4) =
        make_float4(acc[i][4], acc[i][5], acc[i][6], acc[i][7]);
  }
}

// ======== K2: fused A-scan -> CSR(LDS+global) -> sparse attention per row =================
// Scan phase (BW-bound) and gather phase (latency-bound) of different blocks overlap on-CU.
__global__ __launch_bounds__(256) void csr_attn(const float* __restrict__ A,
                                                const float* __restrict__ Z,
                                                int* __restrict__ cols,
                                                int* __restrict__ nnzArr,
                                                float* __restrict__ dinv,
                                                float* __restrict__ aggZ) {
  int row = blockIdx.x;
  int tid = threadIdx.x;
  int lane = tid & 63, wv = tid >> 6;
  __shared__ int scols[CAP];
  __shared__ float zi[PP];
  __shared__ float zz[NSTASH][PP + 1];   // 33 KB
  __shared__ float alpha[KH][CAP];
  __shared__ float red[256];
  __shared__ int wsum[4];

  // own Z row (independent of scan)
  if (tid < PP) zi[tid] = Z[(size_t)row * PP + tid];

  // ---- phase A: scan A row, build CSR in LDS + global ----
  const float* a = A + (size_t)row * NN;
  float4 v[8];
  int cnt = 0;
#pragma unroll
  for (int c = 0; c < 8; ++c) {
    v[c] = *(const float4*)(a + tid * 4 + c * 1024);
    cnt += (v[c].x != 0.f) + (v[c].y != 0.f) + (v[c].z != 0.f) + (v[c].w != 0.f);
  }
  int incl = cnt;
#pragma unroll
  for (int off = 1; off < 64; off <<= 1) {
    int t = __shfl_up(incl, off);
    if (lane >= off) incl += t;
  }
  if (lane == 63) wsum[wv] = incl;
  __syncthreads();
  int base = 0;
#pragma unroll
  for (int w = 0; w < 4; ++w) if (w < wv) base += wsum[w];
  int o = base + incl - cnt;  // exclusive prefix
#pragma unroll
  for (int c = 0; c < 8; ++c) {
    int col = tid * 4 + c * 1024;
    float4 x = v[c];
    if (x.x != 0.f) { if (o < CAP) { scols[o] = col + 0; cols[(size_t)row * CAP + o] = col + 0; } o++; }
    if (x.y != 0.f) { if (o < CAP) { scols[o] = col + 1; cols[(size_t)row * CAP + o] = col + 1; } o++; }
    if (x.z != 0.f) { if (o < CAP) { scols[o] = col + 2; cols[(size_t)row * CAP + o] = col + 2; } o++; }
    if (x.w != 0.f) { if (o < CAP) { scols[o] = col + 3; cols[(size_t)row * CAP + o] = col + 3; } o++; }
  }
  int total = wsum[0] + wsum[1] + wsum[2] + wsum[3];
  int nn = total < CAP ? total : CAP;
  if (tid == 0) {
    nnzArr[row] = nn;
    dinv[row] = 1.0f / sqrtf((float)total);
  }
  __syncthreads();

  // ---- phase B: stash neighbor Z rows (coalesced) ----
  int ns = nn < NSTASH ? nn : NSTASH;
  for (int j = wv; j < ns; j += 4) {
    const float* zj = Z + (size_t)scols[j] * PP;
    float2 x = *(const float2*)(zj + lane * 2);
    zz[j][lane * 2] = x.x;
    zz[j][lane * 2 + 1] = x.y;
  }
  __syncthreads();

  // ---- phase C: scores + wave-parallel softmax (wave wv = head wv) ----
  {
    int k = wv;
    float s0 = -1e30f, s1 = -1e30f;
    if (lane < nn) {
      const float* zs = &zz[lane][k * RR];
      float acc = 0.f;
#pragma unroll
      for (int r = 0; r < RR; r += 4) {
        float4 aa = *(const float4*)(zi + k * RR + r);
        acc += aa.x * zs[r] + aa.y * zs[r + 1] + aa.z * zs[r + 2] + aa.w * zs[r + 3];
      }
      s0 = acc * SCALE;
    }
    int j1 = lane + 64;
    if (j1 < nn) {
      const float* zj = Z + (size_t)scols[j1] * PP + k * RR;
      float acc = 0.f;
#pragma unroll
      for (int r = 0; r < RR; r += 4) {
        float4 aa = *(const float4*)(zi + k * RR + r);
        float4 bb = *(const float4*)(zj + r);
        acc += aa.x * bb.x + aa.y * bb.y + aa.z * bb.z + aa.w * bb.w;
      }
      s1 = acc * SCALE;
    }
    float m = fmaxf(s0, s1);
#pragma unroll
    for (int off = 32; off > 0; off >>= 1) m = fmaxf(m, __shfl_xor(m, off));
    float e0 = (lane < nn) ? expf(s0 - m) : 0.f;
    float e1 = (j1 < nn) ? expf(s1 - m) : 0.f;
    float s = e0 + e1;
#pragma unroll
    for (int off = 32; off > 0; off >>= 1) s += __shfl_xor(s, off);
    float inv = 1.0f / s;
    if (lane < nn) alpha[k][lane] = e0 * inv;
    if (j1 < nn) alpha[k][j1] = e1 * inv;
  }
  __syncthreads();

  // ---- phase D: aggZ[row][p] = sum_j alpha*zz, chain split across 2 halves ----
  {
    int p = tid & 127, hf = tid >> 7;
    float acc = 0.f;
    for (int jj = hf; jj < nn; jj += 2) {
      float zv = (jj < NSTASH) ? zz[jj][p] : Z[(size_t)scols[jj] * PP + p];
      acc += alpha[p >> 5][jj] * zv;
    }
    red[tid] = acc;
  }
  __syncthreads();
  if (tid < PP) aggZ[(size_t)row * PP + tid] = red[tid] + red[tid + 128];
}

// ======== K3: S[row][d] = sum_j dinv[j]*H[j][d]  (lean LDS -> 8 blocks/CU) ================
__global__ __launch_bounds__(256) void sgather(const float* __restrict__ H,
                                               const int* __restrict__ cols,
                                               const int* __restrict__ nnzArr,
                                               const float* __restrict__ dinv,
                                               float* __restrict__ S) {
  int row = blockIdx.x;
  int tid = threadIdx.x;
  int lane = tid & 63, wv = tid >> 6;
  __shared__ int scols[CAP];
  __shared__ float sdinv[CAP];
  __shared__ float sred[4][260];
  int nn = nnzArr[row];
  if (tid < nn) {
    int c = cols[(size_t)row * CAP + tid];
    scols[tid] = c;
    sdinv[tid] = dinv[c];
  }
  __syncthreads();
  float4 acc = make_float4(0.f, 0.f, 0.f, 0.f);
  for (int jj = wv; jj < nn; jj += 4) {
    float4 x = *(const float4*)(H + (size_t)scols[jj] * DD + lane * 4);
    float w = sdinv[jj];
    acc.x += w * x.x; acc.y += w * x.y; acc.z += w * x.z; acc.w += w * x.w;
  }
  *(float4*)(&sred[wv][lane * 4]) = acc;
  __syncthreads();
  float s = sred[0][tid] + sred[1][tid] + sred[2][tid] + sred[3][tid];
  S[(size_t)row * DD + tid] = s;
}

// ======== K4: epilogue GEMM + Laplacian + soft-threshold ==================================
__global__ __launch_bounds__(256) void egemm(const float* __restrict__ A,   // aggZ [N][128]
                                             const float* __restrict__ B,   // B2 [128][256]
                                             const float* __restrict__ Hm,
                                             const float* __restrict__ S,
                                             const float* __restrict__ dinv,
                                             const float* __restrict__ thr,
                                             const float* __restrict__ lambda_p,
                                             float* __restrict__ out) {
  __shared__ float As[32][33];
  __shared__ float Bs[32][128];
  int tid = threadIdx.x;
  int r0 = blockIdx.x * 32;
  int c0 = blockIdx.y * 128;
  int tx = tid & 15, ty = tid >> 4;
  int cx = tx * 8, ry = ty * 2;
  float acc[2][8];
#pragma unroll
  for (int i = 0; i < 2; ++i)
#pragma unroll
    for (int j = 0; j < 8; ++j) acc[i][j] = 0.f;

  for (int k0 = 0; k0 < PP; k0 += 32) {
    {
      int r = tid >> 3;
      int kc = (tid & 7) * 4;
      float4 x = *(const float4*)(A + (size_t)(r0 + r) * PP + k0 + kc);
      As[kc + 0][r] = x.x; As[kc + 1][r] = x.y; As[kc + 2][r] = x.z; As[kc + 3][r] = x.w;
    }
#pragma unroll
    for (int q = 0; q < 4; ++q) {
      int f = tid + 256 * q;
      int kk = f >> 5, pc = (f & 31) * 4;
      *(float4*)(&Bs[kk][pc]) = *(const float4*)(B + (size_t)(k0 + kk) * DD + c0 + pc);
    }
    __syncthreads();
#pragma unroll
    for (int kk = 0; kk < 32; ++kk) {
      float av[2];
      av[0] = As[kk][ry]; av[1] = As[kk][ry + 1];
      float bv[8];
      *(float4*)(bv) = *(const float4*)(&Bs[kk][cx]);
      *(float4*)(bv + 4) = *(const float4*)(&Bs[kk][cx + 4]);
#pragma unroll
      for (int i = 0; i < 2; ++i)
#pragma unroll
        for (int j = 0; j < 8; ++j) acc[i][j] += av[i] * bv[j];
    }
    __syncthreads();
  }
  float lam = lambda_p[0];
  int gc = c0 + cx;
  float4 t0 = *(const float4*)(thr + gc);
  float4 t1 = *(const float4*)(thr + gc + 4);
#pragma unroll
  for (int i = 0; i < 2; ++i) {
    int gr = r0 + ry + i;
    float dv = dinv[gr];
    float4 h0 = *(const float4*)(Hm + (size_t)gr * DD + gc);
    float4 h1 = *(const float4*)(Hm + (size_t)gr * DD + gc + 4);
    float4 s0 = *(const float4*)(S + (size_t)gr * DD + gc);
    float4 s1 = *(const float4*)(S + (size_t)gr * DD + gc + 4);
    float hv[8] = {h0.x, h0.y, h0.z, h0.w, h1.x, h1.y, h1.z, h1.w};
    float sv[8] = {s0.x, s0.y, s0.z, s0.w, s1.x, s1.y, s1.z, s1.w};
    float tv[8] = {t0.x, t0.y, t0.z, t0.w, t1.x, t1.y, t1.z, t1.w};
    float ov[8];
#pragma unroll
    for (int j = 0; j < 8; ++j) {
      float val = hv[j] + ETA * acc[i][j] - ETA * lam * (hv[j] - dv * sv[j]);
      float av = fabsf(val) - tv[j];
      ov[j] = (av > 0.f) ? copysignf(av, val) : 0.f;
    }
    *(float4*)(out + (size_t)gr * DD + gc) = make_float4(ov[0], ov[1], ov[2], ov[3]);
    *(float4*)(out + (size_t)gr * DD + gc + 4) = make_float4(ov[4], ov[5], ov[6], ov[7]);
  }
}

// ======== K5: lap_smooth per-row partials (wave-split float4 gather) ======================
__global__ __launch_bounds__(256) void lap_rows(const float* __restrict__ Hout,
                                                const int* __restrict__ cols,
                                                const int* __restrict__ nnzArr,
                                                const float* __restrict__ dinv,
                                                float* __restrict__ part) {
  int row = blockIdx.x;
  int tid = threadIdx.x;
  int lane = tid & 63, wv = tid >> 6;
  __shared__ int scols[CAP];
  __shared__ float sdinv[CAP];
  __shared__ float sred[4][260];
  int nn = nnzArr[row];
  if (tid < nn) {
    int c = cols[(size_t)row * CAP + tid];
    scols[tid] = c;
    sdinv[tid] = dinv[c];
  }
  __syncthreads();
  float4 acc = make_float4(0.f, 0.f, 0.f, 0.f);
  for (int jj = wv; jj < nn; jj += 4) {
    float4 x = *(const float4*)(Hout + (size_t)scols[jj] * DD + lane * 4);
    float w = sdinv[jj];
    acc.x += w * x.x; acc.y += w * x.y; acc.z += w * x.z; acc.w += w * x.w;
  }
  *(float4*)(&sred[wv][lane * 4]) = acc;
  __syncthreads();
  if (wv == 0) {
    float4 s4;
    s4.x = sred[0][lane * 4 + 0] + sred[1][lane * 4 + 0] + sred[2][lane * 4 + 0] + sred[3][lane * 4 + 0];
    s4.y = sred[0][lane * 4 + 1] + sred[1][lane * 4 + 1] + sred[2][lane * 4 + 1] + sred[3][lane * 4 + 1];
    s4.z = sred[0][lane * 4 + 2] + sred[1][lane * 4 + 2] + sred[2][lane * 4 + 2] + sred[3][lane * 4 + 2];
    s4.w = sred[0][lane * 4 + 3] + sred[1][lane * 4 + 3] + sred[2][lane * 4 + 3] + sred[3][lane * 4 + 3];
    float4 h4 = *(const float4*)(Hout + (size_t)row * DD + lane * 4);
    float dvr = dinv[row];
    float val = h4.x * (h4.x - dvr * s4.x) + h4.y * (h4.y - dvr * s4.y) +
                h4.z * (h4.z - dvr * s4.z) + h4.w * (h4.w - dvr * s4.w);
#pragma unroll
    for (int off = 32; off > 0; off >>= 1) val += __shfl_xor(val, off);
    if (lane == 0) part[row] = val;
  }
}

// ======== K6: deterministic final reduction ==============================================
__global__ __launch_bounds__(256) void finalize(const float* __restrict__ lap_part,
                                                const float* __restrict__ orth_part,
                                                float* __restrict__ out) {
  __shared__ double red[256];
  int tid = threadIdx.x;
  double s = 0.0;
  for (int i = tid; i < NN; i += 256) s += (double)lap_part[i];
  red[tid] = s;
  __syncthreads();
  for (int off = 128; off > 0; off >>= 1) {
    if (tid < off) red[tid] += red[tid + off];
    __syncthreads();
  }
  if (tid == 0) {
    double o = 0.0;
    for (int i = 0; i < 10; ++i) o += (double)orth_part[i];
    out[(size_t)NN * DD] = (float)o;
    out[(size_t)NN * DD + 1] = (float)red[0];
  }
}

extern "C" void kernel_launch(void* const* d_in, const int* in_sizes, int n_in,
                              void* d_out, int out_size, void* d_ws, size_t ws_size,
                              hipStream_t stream) {
  const float* H = (const float*)d_in[0];
  const float* A = (const float*)d_in[1];
  // d_in[2] (dense L) intentionally unused: L reconstructed exactly from A.
  const float* U = (const float*)d_in[3];
  const float* lambda_p = (const float*)d_in[4];
  const float* thr = (const float*)d_in[5];
  float* out = (float*)d_out;

  char* w = (char*)d_ws;
  float* B2 = (float*)w;        w += (size_t)PP * DD * 4;       // 128 KB
  int* cols = (int*)w;          w += (size_t)NN * CAP * 4;      // 4 MB
  int* nnzArr = (int*)w;        w += (size_t)NN * 4;
  float* dinv = (float*)w;      w += (size_t)NN * 4;
  float* Z = (float*)w;         w += (size_t)NN * PP * 4;       // 4 MB
  float* aggZ = (float*)w;      w += (size_t)NN * PP * 4;       // 4 MB
  float* S = (float*)w;         w += (size_t)NN * DD * 4;       // 8 MB
  float* lap_part = (float*)w;  w += (size_t)NN * 4;
  float* orth_part = (float*)w; w += 64;

  zgemm_orth<<<dim3(394), dim3(256), 0, stream>>>(H, U, B2, Z, orth_part);
  csr_attn<<<dim3(NN), dim3(256), 0, stream>>>(A, Z, cols, nnzArr, dinv, aggZ);
  sgather<<<dim3(NN), dim3(256), 0, stream>>>(H, cols, nnzArr, dinv, S);
  egemm<<<dim3(NN / 32, 2), dim3(256), 0, stream>>>(aggZ, B2, H, S, dinv, thr, lambda_p, out);
  lap_rows<<<dim3(NN), dim3(256), 0, stream>>>(out, cols, nnzArr, dinv, lap_part);
  finalize<<<dim3(1), dim3(256), 0, stream>>>(lap_part, orth_part, out);
}

// Round 8
// 174.300 us; speedup vs baseline: 2.4494x; 1.1440x over previous
//
#include <hip/hip_runtime.h>
#include <hip/hip_bf16.h>
#include <math.h>

#define NN 8192
#define DD 256
#define RR 32
#define KH 4
#define PP 128      // KH*RR
#define CAP 128     // max neighbors per row (mean ~34)
#define NSTASH 64   // neighbors stashed in LDS (P(nn>64) ~ 0; graceful fallback)
#define ETA 0.5f
#define SCALE 0.17677669529663687f  // 1/sqrt(32)

// bf16 helpers (explicit bit ops: deterministic, no API ambiguity)
__device__ __forceinline__ unsigned short f2bf(float f) {
  union { float f; unsigned u; } v; v.f = f;
  unsigned r = v.u + 0x7fffu + ((v.u >> 16) & 1u);   // round-to-nearest-even
  return (unsigned short)(r >> 16);
}
__device__ __forceinline__ float bflo(unsigned u) { return __uint_as_float(u << 16); }
__device__ __forceinline__ float bfhi(unsigned u) { return __uint_as_float(u & 0xffff0000u); }

// ======== K1: Z-GEMM->Zb (0..255) | orth (256..265) | B2 (266..393) | Hb (394..649) =======
__global__ __launch_bounds__(256) void zgemm_orth(const float* __restrict__ H,
                                                  const float* __restrict__ U,
                                                  float* __restrict__ B2,
                                                  unsigned short* __restrict__ Zb,
                                                  unsigned short* __restrict__ Hb,
                                                  float* __restrict__ orth_part) {
  __shared__ float smem[5152];
  int tid = threadIdx.x;
  int bx = blockIdx.x;

  if (bx >= 394) {
    // ---- Hb: bf16 mirror of H (coalesced convert) ----
    int base = (bx - 394) * 8192;
#pragma unroll
    for (int q = 0; q < 8; ++q) {
      int idx = base + q * 1024 + tid * 4;
      float4 v = *(const float4*)(H + idx);
      uint2 p;
      p.x = (unsigned)f2bf(v.x) | ((unsigned)f2bf(v.y) << 16);
      p.y = (unsigned)f2bf(v.z) | ((unsigned)f2bf(v.w) << 16);
      *(uint2*)(Hb + idx) = p;
    }
    return;
  }
  if (bx >= 266) {
    // ---- B2 transpose: B2[p][d] = U[k][d][r] ----
    int idx = (bx - 266) * 256 + tid;
    int k = idx / (DD * RR);
    int rem = idx % (DD * RR);
    int d = rem / RR;
    int r = rem % RR;
    B2[(k * RR + r) * DD + d] = U[idx];
    return;
  }
  if (bx >= 256) {
    // ---- orth: one (k<=l) head pair per block; reads U directly ----
    int bid = bx - 256;
    int b = bid, k = 0;
    while (b >= (KH - k)) { b -= (KH - k); k++; }
    int l = k + b;
    float* redo = smem;
    const float* uk = U + (size_t)k * DD * RR;
    const float* ul = U + (size_t)l * DD * RR;
    float acc = 0.f;
#pragma unroll
    for (int q = 0; q < 4; ++q) {
      int e = tid * 4 + q;
      int r = e >> 5, s2 = e & 31;
      float g = 0.f;
      for (int d = 0; d < DD; ++d) g += uk[d * RR + r] * ul[d * RR + s2];
      if (k == l) {
        float c3 = g - (r == s2 ? 1.f : 0.f);
        acc += c3 * c3;
      } else {
        acc += g * g;
      }
    }
    redo[tid] = acc;
    __syncthreads();
    for (int off = 128; off > 0; off >>= 1) {
      if (tid < off) redo[tid] += redo[tid + off];
      __syncthreads();
    }
    if (tid == 0) orth_part[bid] = redo[0];
    return;
  }
  // ---- Z-GEMM: Zb = bf16(H @ B1), B1 read direct from U ----
  float* As = smem;            // [32][33]
  float* Bs = smem + 1056;     // [32][128]
  int r0 = bx * 32;
  int tx = tid & 15, ty = tid >> 4;
  int cx = tx * 8, ry = ty * 2;
  float acc[2][8];
#pragma unroll
  for (int i = 0; i < 2; ++i)
#pragma unroll
    for (int j = 0; j < 8; ++j) acc[i][j] = 0.f;

  for (int k0 = 0; k0 < DD; k0 += 32) {
    {
      int r = tid >> 3;
      int kc = (tid & 7) * 4;
      float4 x = *(const float4*)(H + (size_t)(r0 + r) * DD + k0 + kc);
      As[(kc + 0) * 33 + r] = x.x; As[(kc + 1) * 33 + r] = x.y;
      As[(kc + 2) * 33 + r] = x.z; As[(kc + 3) * 33 + r] = x.w;
    }
#pragma unroll
    for (int q = 0; q < 4; ++q) {
      int f = tid + 256 * q;
      int kk = f >> 5, pc = (f & 31) * 4;
      *(float4*)(&Bs[kk * 128 + pc]) =
          *(const float4*)(U + (size_t)(pc >> 5) * DD * RR + (size_t)(k0 + kk) * RR + (pc & 31));
    }
    __syncthreads();
#pragma unroll
    for (int kk = 0; kk < 32; ++kk) {
      float av[2];
      av[0] = As[kk * 33 + ry]; av[1] = As[kk * 33 + ry + 1];
      float bv[8];
      *(float4*)(bv) = *(const float4*)(&Bs[kk * 128 + cx]);
      *(float4*)(bv + 4) = *(const float4*)(&Bs[kk * 128 + cx + 4]);
#pragma unroll
      for (int i = 0; i < 2; ++i)
#pragma unroll
        for (int j = 0; j < 8; ++j) acc[i][j] += av[i] * bv[j];
    }
    __syncthreads();
  }
#pragma unroll
  for (int i = 0; i < 2; ++i) {
    uint4 p;
    p.x = (unsigned)f2bf(acc[i][0]) | ((unsigned)f2bf(acc[i][1]) << 16);
    p.y = (unsigned)f2bf(acc[i][2]) | ((unsigned)f2bf(acc[i][3]) << 16);
    p.z = (unsigned)f2bf(acc[i][4]) | ((unsigned)f2bf(acc[i][5]) << 16);
    p.w = (unsigned)f2bf(acc[i][6]) | ((unsigned)f2bf(acc[i][7]) << 16);
    *(uint4*)(Zb + (size_t)(r0 + ry + i) * PP + cx) = p;
  }
}

// ======== K2: fused A-scan -> CSR -> sparse attention (bf16 Z gather) =====================
__global__ __launch_bounds__(256) void csr_attn(const float* __restrict__ A,
                                                const unsigned short* __restrict__ Zb,
                                                int* __restrict__ cols,
                                                int* __restrict__ nnzArr,
                                                float* __restrict__ dinv,
                                                float* __restrict__ aggZ) {
  int row = blockIdx.x;
  int tid = threadIdx.x;
  int lane = tid & 63, wv = tid >> 6;
  __shared__ int scols[CAP];
  __shared__ float zi[PP];
  __shared__ unsigned short zzb[NSTASH][130];  // stride 65 words: conflict-free
  __shared__ float alpha[KH][CAP];
  __shared__ float2 redp[4][64];
  __shared__ int wsum[4];

  // own Z row (bf16 -> f32)
  if (tid < PP) zi[tid] = bflo((unsigned)Zb[(size_t)row * PP + tid]);

  // ---- phase A: scan A row, build CSR in LDS + global ----
  const float* a = A + (size_t)row * NN;
  float4 v[8];
  int cnt = 0;
#pragma unroll
  for (int c = 0; c < 8; ++c) {
    v[c] = *(const float4*)(a + tid * 4 + c * 1024);
    cnt += (v[c].x != 0.f) + (v[c].y != 0.f) + (v[c].z != 0.f) + (v[c].w != 0.f);
  }
  int incl = cnt;
#pragma unroll
  for (int off = 1; off < 64; off <<= 1) {
    int t = __shfl_up(incl, off);
    if (lane >= off) incl += t;
  }
  if (lane == 63) wsum[wv] = incl;
  __syncthreads();
  int base = 0;
#pragma unroll
  for (int w = 0; w < 4; ++w) if (w < wv) base += wsum[w];
  int o = base + incl - cnt;
#pragma unroll
  for (int c = 0; c < 8; ++c) {
    int col = tid * 4 + c * 1024;
    float4 x = v[c];
    if (x.x != 0.f) { if (o < CAP) { scols[o] = col + 0; cols[(size_t)row * CAP + o] = col + 0; } o++; }
    if (x.y != 0.f) { if (o < CAP) { scols[o] = col + 1; cols[(size_t)row * CAP + o] = col + 1; } o++; }
    if (x.z != 0.f) { if (o < CAP) { scols[o] = col + 2; cols[(size_t)row * CAP + o] = col + 2; } o++; }
    if (x.w != 0.f) { if (o < CAP) { scols[o] = col + 3; cols[(size_t)row * CAP + o] = col + 3; } o++; }
  }
  int total = wsum[0] + wsum[1] + wsum[2] + wsum[3];
  int nn = total < CAP ? total : CAP;
  if (tid == 0) {
    nnzArr[row] = nn;
    dinv[row] = 1.0f / sqrtf((float)total);
  }
  __syncthreads();

  // ---- phase B: stash neighbor Zb rows (256 B each, coalesced u32/lane) ----
  int ns = nn < NSTASH ? nn : NSTASH;
  for (int j = wv; j < ns; j += 4) {
    unsigned x = *(const unsigned*)(Zb + (size_t)scols[j] * PP + lane * 2);
    *(unsigned*)(&zzb[j][lane * 2]) = x;
  }
  __syncthreads();

  // ---- phase C: scores + wave-parallel softmax (wave wv = head wv) ----
  {
    int k = wv;
    float s0 = -1e30f, s1 = -1e30f;
    if (lane < nn) {
      const unsigned short* zs = &zzb[lane][k * RR];
      float acc = 0.f;
#pragma unroll
      for (int r = 0; r < RR; r += 4) {
        float4 aa = *(const float4*)(zi + k * RR + r);
        unsigned u0 = *(const unsigned*)(zs + r);
        unsigned u1 = *(const unsigned*)(zs + r + 2);
        acc += aa.x * bflo(u0) + aa.y * bfhi(u0) + aa.z * bflo(u1) + aa.w * bfhi(u1);
      }
      s0 = acc * SCALE;
    }
    int j1 = lane + 64;
    if (j1 < nn) {
      const unsigned short* zj = Zb + (size_t)scols[j1] * PP + k * RR;
      float acc = 0.f;
#pragma unroll
      for (int r = 0; r < RR; r += 4) {
        float4 aa = *(const float4*)(zi + k * RR + r);
        unsigned u0 = *(const unsigned*)(zj + r);
        unsigned u1 = *(const unsigned*)(zj + r + 2);
        acc += aa.x * bflo(u0) + aa.y * bfhi(u0) + aa.z * bflo(u1) + aa.w * bfhi(u1);
      }
      s1 = acc * SCALE;
    }
    float m = fmaxf(s0, s1);
#pragma unroll
    for (int off = 32; off > 0; off >>= 1) m = fmaxf(m, __shfl_xor(m, off));
    float e0 = (lane < nn) ? expf(s0 - m) : 0.f;
    float e1 = (j1 < nn) ? expf(s1 - m) : 0.f;
    float s = e0 + e1;
#pragma unroll
    for (int off = 32; off > 0; off >>= 1) s += __shfl_xor(s, off);
    float inv = 1.0f / s;
    if (lane < nn) alpha[k][lane] = e0 * inv;
    if (j1 < nn) alpha[k][j1] = e1 * inv;
  }
  __syncthreads();

  // ---- phase D: aggZ = sum_j alpha*zz; thread owns col-pair c2, 4-way jj split ----
  {
    int c2 = tid & 63, hf = tid >> 6;
    int hd = c2 >> 4;                     // head of cols {2c2, 2c2+1}
    float a0 = 0.f, a1 = 0.f;
    for (int jj = hf; jj < nn; jj += 4) {
      unsigned u;
      if (jj < NSTASH) u = *(const unsigned*)(&zzb[jj][c2 * 2]);
      else u = *(const unsigned*)(Zb + (size_t)scols[jj] * PP + c2 * 2);
      float al = alpha[hd][jj];
      a0 += al * bflo(u);
      a1 += al * bfhi(u);
    }
    redp[hf][c2] = make_float2(a0, a1);
  }
  __syncthreads();
  if (tid < 64) {
    float2 r0 = redp[0][tid], r1 = redp[1][tid], r2 = redp[2][tid], r3 = redp[3][tid];
    float2 s2 = make_float2(r0.x + r1.x + r2.x + r3.x, r0.y + r1.y + r2.y + r3.y);
    *(float2*)(aggZ + (size_t)row * PP + tid * 2) = s2;
  }
}

// ======== K3: S[row][d] = sum_j dinv[j]*Hb[j][d]  (bf16 gather) ===========================
__global__ __launch_bounds__(256) void sgather(const unsigned short* __restrict__ Hb,
                                               const int* __restrict__ cols,
                                               const int* __restrict__ nnzArr,
                                               const float* __restrict__ dinv,
                                               float* __restrict__ S) {
  int row = blockIdx.x;
  int tid = threadIdx.x;
  int lane = tid & 63, wv = tid >> 6;
  __shared__ int scols[CAP];
  __shared__ float sdinv[CAP];
  __shared__ float sred[4][260];
  int nn = nnzArr[row];
  if (tid < nn) {
    int c = cols[(size_t)row * CAP + tid];
    scols[tid] = c;
    sdinv[tid] = dinv[c];
  }
  __syncthreads();
  float4 acc = make_float4(0.f, 0.f, 0.f, 0.f);
  for (int jj = wv; jj < nn; jj += 4) {
    uint2 u = *(const uint2*)(Hb + (size_t)scols[jj] * DD + lane * 4);
    float w = sdinv[jj];
    acc.x += w * bflo(u.x); acc.y += w * bfhi(u.x);
    acc.z += w * bflo(u.y); acc.w += w * bfhi(u.y);
  }
  *(float4*)(&sred[wv][lane * 4]) = acc;
  __syncthreads();
  float s = sred[0][tid] + sred[1][tid] + sred[2][tid] + sred[3][tid];
  S[(size_t)row * DD + tid] = s;
}

// ======== K4: epilogue GEMM + Laplacian + soft-threshold; writes out f32 + Houtb bf16 =====
__global__ __launch_bounds__(256) void egemm(const float* __restrict__ A,   // aggZ [N][128]
                                             const float* __restrict__ B,   // B2 [128][256]
                                             const float* __restrict__ Hm,
                                             const float* __restrict__ S,
                                             const float* __restrict__ dinv,
                                             const float* __restrict__ thr,
                                             const float* __restrict__ lambda_p,
                                             float* __restrict__ out,
                                             unsigned short* __restrict__ Houtb) {
  __shared__ float As[32][33];
  __shared__ float Bs[32][128];
  int tid = threadIdx.x;
  int r0 = blockIdx.x * 32;
  int c0 = blockIdx.y * 128;
  int tx = tid & 15, ty = tid >> 4;
  int cx = tx * 8, ry = ty * 2;
  float acc[2][8];
#pragma unroll
  for (int i = 0; i < 2; ++i)
#pragma unroll
    for (int j = 0; j < 8; ++j) acc[i][j] = 0.f;

  for (int k0 = 0; k0 < PP; k0 += 32) {
    {
      int r = tid >> 3;
      int kc = (tid & 7) * 4;
      float4 x = *(const float4*)(A + (size_t)(r0 + r) * PP + k0 + kc);
      As[kc + 0][r] = x.x; As[kc + 1][r] = x.y; As[kc + 2][r] = x.z; As[kc + 3][r] = x.w;
    }
#pragma unroll
    for (int q = 0; q < 4; ++q) {
      int f = tid + 256 * q;
      int kk = f >> 5, pc = (f & 31) * 4;
      *(float4*)(&Bs[kk][pc]) = *(const float4*)(B + (size_t)(k0 + kk) * DD + c0 + pc);
    }
    __syncthreads();
#pragma unroll
    for (int kk = 0; kk < 32; ++kk) {
      float av[2];
      av[0] = As[kk][ry]; av[1] = As[kk][ry + 1];
      float bv[8];
      *(float4*)(bv) = *(const float4*)(&Bs[kk][cx]);
      *(float4*)(bv + 4) = *(const float4*)(&Bs[kk][cx + 4]);
#pragma unroll
      for (int i = 0; i < 2; ++i)
#pragma unroll
        for (int j = 0; j < 8; ++j) acc[i][j] += av[i] * bv[j];
    }
    __syncthreads();
  }
  float lam = lambda_p[0];
  int gc = c0 + cx;
  float4 t0 = *(const float4*)(thr + gc);
  float4 t1 = *(const float4*)(thr + gc + 4);
#pragma unroll
  for (int i = 0; i < 2; ++i) {
    int gr = r0 + ry + i;
    float dv = dinv[gr];
    float4 h0 = *(const float4*)(Hm + (size_t)gr * DD + gc);
    float4 h1 = *(const float4*)(Hm + (size_t)gr * DD + gc + 4);
    float4 s0 = *(const float4*)(S + (size_t)gr * DD + gc);
    float4 s1 = *(const float4*)(S + (size_t)gr * DD + gc + 4);
    float hv[8] = {h0.x, h0.y, h0.z, h0.w, h1.x, h1.y, h1.z, h1.w};
    float sv[8] = {s0.x, s0.y, s0.z, s0.w, s1.x, s1.y, s1.z, s1.w};
    float tv[8] = {t0.x, t0.y, t0.z, t0.w, t1.x, t1.y, t1.z, t1.w};
    float ov[8];
#pragma unroll
    for (int j = 0; j < 8; ++j) {
      float val = hv[j] + ETA * acc[i][j] - ETA * lam * (hv[j] - dv * sv[j]);
      float av = fabsf(val) - tv[j];
      ov[j] = (av > 0.f) ? copysignf(av, val) : 0.f;
    }
    *(float4*)(out + (size_t)gr * DD + gc) = make_float4(ov[0], ov[1], ov[2], ov[3]);
    *(float4*)(out + (size_t)gr * DD + gc + 4) = make_float4(ov[4], ov[5], ov[6], ov[7]);
    uint4 p;
    p.x = (unsigned)f2bf(ov[0]) | ((unsigned)f2bf(ov[1]) << 16);
    p.y = (unsigned)f2bf(ov[2]) | ((unsigned)f2bf(ov[3]) << 16);
    p.z = (unsigned)f2bf(ov[4]) | ((unsigned)f2bf(ov[5]) << 16);
    p.w = (unsigned)f2bf(ov[6]) | ((unsigned)f2bf(ov[7]) << 16);
    *(uint4*)(Houtb + (size_t)gr * DD + gc) = p;
  }
}

// ======== K5: lap_smooth per-row partials (bf16 neighbor gather) ==========================
__global__ __launch_bounds__(256) void lap_rows(const float* __restrict__ Hout,
                                                const unsigned short* __restrict__ Houtb,
                                                const int* __restrict__ cols,
                                                const int* __restrict__ nnzArr,
                                                const float* __restrict__ dinv,
                                                float* __restrict__ part) {
  int row = blockIdx.x;
  int tid = threadIdx.x;
  int lane = tid & 63, wv = tid >> 6;
  __shared__ int scols[CAP];
  __shared__ float sdinv[CAP];
  __shared__ float sred[4][260];
  int nn = nnzArr[row];
  if (tid < nn) {
    int c = cols[(size_t)row * CAP + tid];
    scols[tid] = c;
    sdinv[tid] = dinv[c];
  }
  __syncthreads();
  float4 acc = make_float4(0.f, 0.f, 0.f, 0.f);
  for (int jj = wv; jj < nn; jj += 4) {
    uint2 u = *(const uint2*)(Houtb + (size_t)scols[jj] * DD + lane * 4);
    float w = sdinv[jj];
    acc.x += w * bflo(u.x); acc.y += w * bfhi(u.x);
    acc.z += w * bflo(u.y); acc.w += w * bfhi(u.y);
  }
  *(float4*)(&sred[wv][lane * 4]) = acc;
  __syncthreads();
  if (wv == 0) {
    float4 s4;
    s4.x = sred[0][lane * 4 + 0] + sred[1][lane * 4 + 0] + sred[2][lane * 4 + 0] + sred[3][lane * 4 + 0];
    s4.y = sred[0][lane * 4 + 1] + sred[1][lane * 4 + 1] + sred[2][lane * 4 + 1] + sred[3][lane * 4 + 1];
    s4.z = sred[0][lane * 4 + 2] + sred[1][lane * 4 + 2] + sred[2][lane * 4 + 2] + sred[3][lane * 4 + 2];
    s4.w = sred[0][lane * 4 + 3] + sred[1][lane * 4 + 3] + sred[2][lane * 4 + 3] + sred[3][lane * 4 + 3];
    float4 h4 = *(const float4*)(Hout + (size_t)row * DD + lane * 4);
    float dvr = dinv[row];
    float val = h4.x * (h4.x - dvr * s4.x) + h4.y * (h4.y - dvr * s4.y) +
                h4.z * (h4.z - dvr * s4.z) + h4.w * (h4.w - dvr * s4.w);
#pragma unroll
    for (int off = 32; off > 0; off >>= 1) val += __shfl_xor(val, off);
    if (lane == 0) part[row] = val;
  }
}

// ======== K6: deterministic final reduction ==============================================
__global__ __launch_bounds__(256) void finalize(const float* __restrict__ lap_part,
                                                const float* __restrict__ orth_part,
                                                float* __restrict__ out) {
  __shared__ double red[256];
  int tid = threadIdx.x;
  double s = 0.0;
  for (int i = tid; i < NN; i += 256) s += (double)lap_part[i];
  red[tid] = s;
  __syncthreads();
  for (int off = 128; off > 0; off >>= 1) {
    if (tid < off) red[tid] += red[tid + off];
    __syncthreads();
  }
  if (tid == 0) {
    double o = 0.0;
    for (int i = 0; i < 10; ++i) o += (double)orth_part[i];
    out[(size_t)NN * DD] = (float)o;
    out[(size_t)NN * DD + 1] = (float)red[0];
  }
}

extern "C" void kernel_launch(void* const* d_in, const int* in_sizes, int n_in,
                              void* d_out, int out_size, void* d_ws, size_t ws_size,
                              hipStream_t stream) {
  const float* H = (const float*)d_in[0];
  const float* A = (const float*)d_in[1];
  // d_in[2] (dense L) intentionally unused: L reconstructed exactly from A.
  const float* U = (const float*)d_in[3];
  const float* lambda_p = (const float*)d_in[4];
  const float* thr = (const float*)d_in[5];
  float* out = (float*)d_out;

  char* w = (char*)d_ws;
  float* B2 = (float*)w;             w += (size_t)PP * DD * 4;     // 128 KB
  int* cols = (int*)w;               w += (size_t)NN * CAP * 4;    // 4 MB
  int* nnzArr = (int*)w;             w += (size_t)NN * 4;
  float* dinv = (float*)w;           w += (size_t)NN * 4;
  unsigned short* Zb = (unsigned short*)w;   w += (size_t)NN * PP * 2;   // 2 MB
  unsigned short* Hb = (unsigned short*)w;   w += (size_t)NN * DD * 2;   // 4 MB
  unsigned short* Houtb = (unsigned short*)w; w += (size_t)NN * DD * 2;  // 4 MB
  float* aggZ = (float*)w;           w += (size_t)NN * PP * 4;     // 4 MB
  float* S = (float*)w;              w += (size_t)NN * DD * 4;     // 8 MB
  float* lap_part = (float*)w;       w += (size_t)NN * 4;
  float* orth_part = (float*)w;      w += 64;

  zgemm_orth<<<dim3(650), dim3(256), 0, stream>>>(H, U, B2, Zb, Hb, orth_part);
  csr_attn<<<dim3(NN), dim3(256), 0, stream>>>(A, Zb, cols, nnzArr, dinv, aggZ);
  sgather<<<dim3(NN), dim3(256), 0, stream>>>(Hb, cols, nnzArr, dinv, S);
  egemm<<<dim3(NN / 32, 2), dim3(256), 0, stream>>>(aggZ, B2, H, S, dinv, thr, lambda_p,
                                                    out, Houtb);
  lap_rows<<<dim3(NN), dim3(256), 0, stream>>>(out, Houtb, cols, nnzArr, dinv, lap_part);
  finalize<<<dim3(1), dim3(256), 0, stream>>>(lap_part, orth_part, out);
}

// Round 9
// 159.949 us; speedup vs baseline: 2.6692x; 1.0897x over previous
//
#include <hip/hip_runtime.h>
#include <hip/hip_bf16.h>
#include <math.h>

#define NN 8192
#define DD 256
#define RR 32
#define KH 4
#define PP 128      // KH*RR
#define CAP 128     // max neighbors per row (mean ~34)
#define CAPL 128    // per-row capacity of lower/upper half-lists
#define NSTASH 64   // neighbors stashed in LDS (P(nn>64) ~ 0; graceful fallback)
#define ETA 0.5f
#define SCALE 0.17677669529663687f  // 1/sqrt(32)

// bf16 helpers (explicit bit ops: deterministic)
__device__ __forceinline__ unsigned short f2bf(float f) {
  union { float f; unsigned u; } v; v.f = f;
  unsigned r = v.u + 0x7fffu + ((v.u >> 16) & 1u);   // round-to-nearest-even
  return (unsigned short)(r >> 16);
}
__device__ __forceinline__ float bflo(unsigned u) { return __uint_as_float(u << 16); }
__device__ __forceinline__ float bfhi(unsigned u) { return __uint_as_float(u & 0xffff0000u); }

// ======== K1: Z-GEMM (0..255) | orth (256..265) | B2 (266..393) | Hb (394..649)
//              | symmetric lower-triangle A-scan (650..8841) ==============================
__global__ __launch_bounds__(256) void zgemm_scan(const float* __restrict__ A,
                                                  const float* __restrict__ H,
                                                  const float* __restrict__ U,
                                                  float* __restrict__ B2,
                                                  unsigned short* __restrict__ Zb,
                                                  unsigned short* __restrict__ Hb,
                                                  float* __restrict__ orth_part,
                                                  int* __restrict__ lowCols,
                                                  int* __restrict__ lowCnt,
                                                  int* __restrict__ upCols,
                                                  int* __restrict__ upCnt) {
  __shared__ float smem[5152];
  int tid = threadIdx.x;
  int bx = blockIdx.x;
  int lane = tid & 63, wv = tid >> 6;

  if (bx >= 650) {
    // ---- symmetric scan: row's strict-lower triangle only (134 MB total) ----
    // reversed order: longest scans dispatch first
    int row = (NN - 1) - (bx - 650);
    const float* a = A + (size_t)row * NN;
    __shared__ int wsum2[4];
    __shared__ int sbase;
    if (tid == 0) sbase = 0;
    int nch = (row >> 10) + 1;
    for (int c = 0; c < nch; ++c) {
      int g0 = c * 1024 + tid * 4;
      float4 x = *(const float4*)(a + g0);
      int m0 = (g0 + 0 < row) && (x.x != 0.f);
      int m1 = (g0 + 1 < row) && (x.y != 0.f);
      int m2 = (g0 + 2 < row) && (x.z != 0.f);
      int m3 = (g0 + 3 < row) && (x.w != 0.f);
      int cnt = m0 + m1 + m2 + m3;
      int incl = cnt;
#pragma unroll
      for (int off = 1; off < 64; off <<= 1) {
        int t = __shfl_up(incl, off);
        if (lane >= off) incl += t;
      }
      if (lane == 63) wsum2[wv] = incl;
      __syncthreads();
      int base = sbase;
#pragma unroll
      for (int w = 0; w < 4; ++w) if (w < wv) base += wsum2[w];
      int o = base + incl - cnt;
      int chunkTot = wsum2[0] + wsum2[1] + wsum2[2] + wsum2[3];
      if (m0) { int col = g0 + 0; if (o < CAPL) { lowCols[(size_t)row * CAPL + o] = col; int s = atomicAdd(&upCnt[col], 1); if (s < CAPL) upCols[(size_t)col * CAPL + s] = row; } o++; }
      if (m1) { int col = g0 + 1; if (o < CAPL) { lowCols[(size_t)row * CAPL + o] = col; int s = atomicAdd(&upCnt[col], 1); if (s < CAPL) upCols[(size_t)col * CAPL + s] = row; } o++; }
      if (m2) { int col = g0 + 2; if (o < CAPL) { lowCols[(size_t)row * CAPL + o] = col; int s = atomicAdd(&upCnt[col], 1); if (s < CAPL) upCols[(size_t)col * CAPL + s] = row; } o++; }
      if (m3) { int col = g0 + 3; if (o < CAPL) { lowCols[(size_t)row * CAPL + o] = col; int s = atomicAdd(&upCnt[col], 1); if (s < CAPL) upCols[(size_t)col * CAPL + s] = row; } o++; }
      __syncthreads();
      if (tid == 0) sbase = base + chunkTot;   // base here == sbase (wv==0 path adds nothing)
    }
    __syncthreads();
    if (tid == 0) lowCnt[row] = sbase;
    return;
  }
  if (bx >= 394) {
    // ---- Hb: bf16 mirror of H ----
    int base = (bx - 394) * 8192;
#pragma unroll
    for (int q = 0; q < 8; ++q) {
      int idx = base + q * 1024 + tid * 4;
      float4 v = *(const float4*)(H + idx);
      uint2 p;
      p.x = (unsigned)f2bf(v.x) | ((unsigned)f2bf(v.y) << 16);
      p.y = (unsigned)f2bf(v.z) | ((unsigned)f2bf(v.w) << 16);
      *(uint2*)(Hb + idx) = p;
    }
    return;
  }
  if (bx >= 266) {
    // ---- B2 transpose ----
    int idx = (bx - 266) * 256 + tid;
    int k = idx / (DD * RR);
    int rem = idx % (DD * RR);
    int d = rem / RR;
    int r = rem % RR;
    B2[(k * RR + r) * DD + d] = U[idx];
    return;
  }
  if (bx >= 256) {
    // ---- orth ----
    int bid = bx - 256;
    int b = bid, k = 0;
    while (b >= (KH - k)) { b -= (KH - k); k++; }
    int l = k + b;
    float* redo = smem;
    const float* uk = U + (size_t)k * DD * RR;
    const float* ul = U + (size_t)l * DD * RR;
    float acc = 0.f;
#pragma unroll
    for (int q = 0; q < 4; ++q) {
      int e = tid * 4 + q;
      int r = e >> 5, s2 = e & 31;
      float g = 0.f;
      for (int d = 0; d < DD; ++d) g += uk[d * RR + r] * ul[d * RR + s2];
      if (k == l) {
        float c3 = g - (r == s2 ? 1.f : 0.f);
        acc += c3 * c3;
      } else {
        acc += g * g;
      }
    }
    redo[tid] = acc;
    __syncthreads();
    for (int off = 128; off > 0; off >>= 1) {
      if (tid < off) redo[tid] += redo[tid + off];
      __syncthreads();
    }
    if (tid == 0) orth_part[bid] = redo[0];
    return;
  }
  // ---- Z-GEMM: Zb = bf16(H @ B1) ----
  float* As = smem;
  float* Bs = smem + 1056;
  int r0 = bx * 32;
  int tx = tid & 15, ty = tid >> 4;
  int cx = tx * 8, ry = ty * 2;
  float acc[2][8];
#pragma unroll
  for (int i = 0; i < 2; ++i)
#pragma unroll
    for (int j = 0; j < 8; ++j) acc[i][j] = 0.f;

  for (int k0 = 0; k0 < DD; k0 += 32) {
    {
      int r = tid >> 3;
      int kc = (tid & 7) * 4;
      float4 x = *(const float4*)(H + (size_t)(r0 + r) * DD + k0 + kc);
      As[(kc + 0) * 33 + r] = x.x; As[(kc + 1) * 33 + r] = x.y;
      As[(kc + 2) * 33 + r] = x.z; As[(kc + 3) * 33 + r] = x.w;
    }
#pragma unroll
    for (int q = 0; q < 4; ++q) {
      int f = tid + 256 * q;
      int kk = f >> 5, pc = (f & 31) * 4;
      *(float4*)(&Bs[kk * 128 + pc]) =
          *(const float4*)(U + (size_t)(pc >> 5) * DD * RR + (size_t)(k0 + kk) * RR + (pc & 31));
    }
    __syncthreads();
#pragma unroll
    for (int kk = 0; kk < 32; ++kk) {
      float av[2];
      av[0] = As[kk * 33 + ry]; av[1] = As[kk * 33 + ry + 1];
      float bv[8];
      *(float4*)(bv) = *(const float4*)(&Bs[kk * 128 + cx]);
      *(float4*)(bv + 4) = *(const float4*)(&Bs[kk * 128 + cx + 4]);
#pragma unroll
      for (int i = 0; i < 2; ++i)
#pragma unroll
        for (int j = 0; j < 8; ++j) acc[i][j] += av[i] * bv[j];
    }
    __syncthreads();
  }
#pragma unroll
  for (int i = 0; i < 2; ++i) {
    uint4 p;
    p.x = (unsigned)f2bf(acc[i][0]) | ((unsigned)f2bf(acc[i][1]) << 16);
    p.y = (unsigned)f2bf(acc[i][2]) | ((unsigned)f2bf(acc[i][3]) << 16);
    p.z = (unsigned)f2bf(acc[i][4]) | ((unsigned)f2bf(acc[i][5]) << 16);
    p.w = (unsigned)f2bf(acc[i][6]) | ((unsigned)f2bf(acc[i][7]) << 16);
    *(uint4*)(Zb + (size_t)(r0 + ry + i) * PP + cx) = p;
  }
}

// ======== K2: assemble CSR (lower ++ diag ++ rank-sorted upper) -> attention ==============
__global__ __launch_bounds__(256) void csr_attn(const unsigned short* __restrict__ Zb,
                                                const int* __restrict__ lowCols,
                                                const int* __restrict__ lowCnt,
                                                const int* __restrict__ upCols,
                                                const int* __restrict__ upCnt,
                                                int* __restrict__ cols,
                                                int* __restrict__ nnzArr,
                                                float* __restrict__ dinv,
                                                float* __restrict__ aggZ) {
  int row = blockIdx.x;
  int tid = threadIdx.x;
  int lane = tid & 63, wv = tid >> 6;
  __shared__ int scols[CAP];
  __shared__ int utmp[CAPL];
  __shared__ float zi[PP];
  __shared__ unsigned short zzb[NSTASH][130];  // stride 65 words: conflict-free
  __shared__ float alpha[KH][CAP];
  __shared__ float2 redp[4][64];

  // own Z row (bf16 -> f32)
  if (tid < PP) zi[tid] = bflo((unsigned)Zb[(size_t)row * PP + tid]);

  // ---- assemble neighbor list: ascending == identical order to a dense scan ----
  int lcT = lowCnt[row];
  int ucT = upCnt[row];
  int lc = lcT < (CAP - 1) ? lcT : (CAP - 1);
  for (int t = tid; t < lc; t += 256) scols[t] = lowCols[(size_t)row * CAPL + t];
  if (tid == 0) scols[lc] = row;                       // diagonal (always present)
  int ucR = ucT < CAPL ? ucT : CAPL;
  for (int t = tid; t < ucR; t += 256) utmp[t] = upCols[(size_t)row * CAPL + t];
  __syncthreads();
  for (int t = tid; t < ucR; t += 256) {
    int e = utmp[t], r = 0;
    for (int q = 0; q < ucR; ++q) r += (utmp[q] < e);  // distinct entries -> exact rank
    int pos = lc + 1 + r;
    if (pos < CAP) scols[pos] = e;
  }
  int total = lcT + 1 + ucT;
  int nn = total < CAP ? total : CAP;
  if (tid == 0) {
    nnzArr[row] = nn;
    dinv[row] = 1.0f / sqrtf((float)total);
  }
  __syncthreads();
  for (int t = tid; t < nn; t += 256) cols[(size_t)row * CAP + t] = scols[t];

  // ---- stash neighbor Zb rows (coalesced u32/lane) ----
  int ns = nn < NSTASH ? nn : NSTASH;
  for (int j = wv; j < ns; j += 4) {
    unsigned x = *(const unsigned*)(Zb + (size_t)scols[j] * PP + lane * 2);
    *(unsigned*)(&zzb[j][lane * 2]) = x;
  }
  __syncthreads();

  // ---- scores + wave-parallel softmax (wave wv = head wv) ----
  {
    int k = wv;
    float s0 = -1e30f, s1 = -1e30f;
    if (lane < nn) {
      const unsigned short* zs = &zzb[lane][k * RR];
      float acc = 0.f;
#pragma unroll
      for (int r = 0; r < RR; r += 4) {
        float4 aa = *(const float4*)(zi + k * RR + r);
        unsigned u0 = *(const unsigned*)(zs + r);
        unsigned u1 = *(const unsigned*)(zs + r + 2);
        acc += aa.x * bflo(u0) + aa.y * bfhi(u0) + aa.z * bflo(u1) + aa.w * bfhi(u1);
      }
      s0 = acc * SCALE;
    }
    int j1 = lane + 64;
    if (j1 < nn) {
      const unsigned short* zj = Zb + (size_t)scols[j1] * PP + k * RR;
      float acc = 0.f;
#pragma unroll
      for (int r = 0; r < RR; r += 4) {
        float4 aa = *(const float4*)(zi + k * RR + r);
        unsigned u0 = *(const unsigned*)(zj + r);
        unsigned u1 = *(const unsigned*)(zj + r + 2);
        acc += aa.x * bflo(u0) + aa.y * bfhi(u0) + aa.z * bflo(u1) + aa.w * bfhi(u1);
      }
      s1 = acc * SCALE;
    }
    float m = fmaxf(s0, s1);
#pragma unroll
    for (int off = 32; off > 0; off >>= 1) m = fmaxf(m, __shfl_xor(m, off));
    float e0 = (lane < nn) ? expf(s0 - m) : 0.f;
    float e1 = (j1 < nn) ? expf(s1 - m) : 0.f;
    float s = e0 + e1;
#pragma unroll
    for (int off = 32; off > 0; off >>= 1) s += __shfl_xor(s, off);
    float inv = 1.0f / s;
    if (lane < nn) alpha[k][lane] = e0 * inv;
    if (j1 < nn) alpha[k][j1] = e1 * inv;
  }
  __syncthreads();

  // ---- aggZ = sum_j alpha*zz; thread owns col-pair, 4-way jj split ----
  {
    int c2 = tid & 63, hf = tid >> 6;
    int hd = c2 >> 4;
    float a0 = 0.f, a1 = 0.f;
    for (int jj = hf; jj < nn; jj += 4) {
      unsigned u;
      if (jj < NSTASH) u = *(const unsigned*)(&zzb[jj][c2 * 2]);
      else u = *(const unsigned*)(Zb + (size_t)scols[jj] * PP + c2 * 2);
      float al = alpha[hd][jj];
      a0 += al * bflo(u);
      a1 += al * bfhi(u);
    }
    redp[hf][c2] = make_float2(a0, a1);
  }
  __syncthreads();
  if (tid < 64) {
    float2 r0 = redp[0][tid], r1 = redp[1][tid], r2 = redp[2][tid], r3 = redp[3][tid];
    float2 s2 = make_float2(r0.x + r1.x + r2.x + r3.x, r0.y + r1.y + r2.y + r3.y);
    *(float2*)(aggZ + (size_t)row * PP + tid * 2) = s2;
  }
}

// ======== K3: S[row][d] = sum_j dinv[j]*Hb[j][d]  (bf16 gather) ===========================
__global__ __launch_bounds__(256) void sgather(const unsigned short* __restrict__ Hb,
                                               const int* __restrict__ cols,
                                               const int* __restrict__ nnzArr,
                                               const float* __restrict__ dinv,
                                               float* __restrict__ S) {
  int row = blockIdx.x;
  int tid = threadIdx.x;
  int lane = tid & 63, wv = tid >> 6;
  __shared__ int scols[CAP];
  __shared__ float sdinv[CAP];
  __shared__ float sred[4][260];
  int nn = nnzArr[row];
  if (tid < nn) {
    int c = cols[(size_t)row * CAP + tid];
    scols[tid] = c;
    sdinv[tid] = dinv[c];
  }
  __syncthreads();
  float4 acc = make_float4(0.f, 0.f, 0.f, 0.f);
  for (int jj = wv; jj < nn; jj += 4) {
    uint2 u = *(const uint2*)(Hb + (size_t)scols[jj] * DD + lane * 4);
    float w = sdinv[jj];
    acc.x += w * bflo(u.x); acc.y += w * bfhi(u.x);
    acc.z += w * bflo(u.y); acc.w += w * bfhi(u.y);
  }
  *(float4*)(&sred[wv][lane * 4]) = acc;
  __syncthreads();
  float s = sred[0][tid] + sred[1][tid] + sred[2][tid] + sred[3][tid];
  S[(size_t)row * DD + tid] = s;
}

// ======== K4: epilogue GEMM + Laplacian + soft-threshold; writes out f32 + Houtb bf16 =====
__global__ __launch_bounds__(256) void egemm(const float* __restrict__ A,   // aggZ [N][128]
                                             const float* __restrict__ B,   // B2 [128][256]
                                             const float* __restrict__ Hm,
                                             const float* __restrict__ S,
                                             const float* __restrict__ dinv,
                                             const float* __restrict__ thr,
                                             const float* __restrict__ lambda_p,
                                             float* __restrict__ out,
                                             unsigned short* __restrict__ Houtb) {
  __shared__ float As[32][33];
  __shared__ float Bs[32][128];
  int tid = threadIdx.x;
  int r0 = blockIdx.x * 32;
  int c0 = blockIdx.y * 128;
  int tx = tid & 15, ty = tid >> 4;
  int cx = tx * 8, ry = ty * 2;
  float acc[2][8];
#pragma unroll
  for (int i = 0; i < 2; ++i)
#pragma unroll
    for (int j = 0; j < 8; ++j) acc[i][j] = 0.f;

  for (int k0 = 0; k0 < PP; k0 += 32) {
    {
      int r = tid >> 3;
      int kc = (tid & 7) * 4;
      float4 x = *(const float4*)(A + (size_t)(r0 + r) * PP + k0 + kc);
      As[kc + 0][r] = x.x; As[kc + 1][r] = x.y; As[kc + 2][r] = x.z; As[kc + 3][r] = x.w;
    }
#pragma unroll
    for (int q = 0; q < 4; ++q) {
      int f = tid + 256 * q;
      int kk = f >> 5, pc = (f & 31) * 4;
      *(float4*)(&Bs[kk][pc]) = *(const float4*)(B + (size_t)(k0 + kk) * DD + c0 + pc);
    }
    __syncthreads();
#pragma unroll
    for (int kk = 0; kk < 32; ++kk) {
      float av[2];
      av[0] = As[kk][ry]; av[1] = As[kk][ry + 1];
      float bv[8];
      *(float4*)(bv) = *(const float4*)(&Bs[kk][cx]);
      *(float4*)(bv + 4) = *(const float4*)(&Bs[kk][cx + 4]);
#pragma unroll
      for (int i = 0; i < 2; ++i)
#pragma unroll
        for (int j = 0; j < 8; ++j) acc[i][j] += av[i] * bv[j];
    }
    __syncthreads();
  }
  float lam = lambda_p[0];
  int gc = c0 + cx;
  float4 t0 = *(const float4*)(thr + gc);
  float4 t1 = *(const float4*)(thr + gc + 4);
#pragma unroll
  for (int i = 0; i < 2; ++i) {
    int gr = r0 + ry + i;
    float dv = dinv[gr];
    float4 h0 = *(const float4*)(Hm + (size_t)gr * DD + gc);
    float4 h1 = *(const float4*)(Hm + (size_t)gr * DD + gc + 4);
    float4 s0 = *(const float4*)(S + (size_t)gr * DD + gc);
    float4 s1 = *(const float4*)(S + (size_t)gr * DD + gc + 4);
    float hv[8] = {h0.x, h0.y, h0.z, h0.w, h1.x, h1.y, h1.z, h1.w};
    float sv[8] = {s0.x, s0.y, s0.z, s0.w, s1.x, s1.y, s1.z, s1.w};
    float tv[8] = {t0.x, t0.y, t0.z, t0.w, t1.x, t1.y, t1.z, t1.w};
    float ov[8];
#pragma unroll
    for (int j = 0; j < 8; ++j) {
      float val = hv[j] + ETA * acc[i][j] - ETA * lam * (hv[j] - dv * sv[j]);
      float av = fabsf(val) - tv[j];
      ov[j] = (av > 0.f) ? copysignf(av, val) : 0.f;
    }
    *(float4*)(out + (size_t)gr * DD + gc) = make_float4(ov[0], ov[1], ov[2], ov[3]);
    *(float4*)(out + (size_t)gr * DD + gc + 4) = make_float4(ov[4], ov[5], ov[6], ov[7]);
    uint4 p;
    p.x = (unsigned)f2bf(ov[0]) | ((unsigned)f2bf(ov[1]) << 16);
    p.y = (unsigned)f2bf(ov[2]) | ((unsigned)f2bf(ov[3]) << 16);
    p.z = (unsigned)f2bf(ov[4]) | ((unsigned)f2bf(ov[5]) << 16);
    p.w = (unsigned)f2bf(ov[6]) | ((unsigned)f2bf(ov[7]) << 16);
    *(uint4*)(Houtb + (size_t)gr * DD + gc) = p;
  }
}

// ======== K5: lap_smooth per-row partials (bf16 neighbor gather) ==========================
__global__ __launch_bounds__(256) void lap_rows(const float* __restrict__ Hout,
                                                const unsigned short* __restrict__ Houtb,
                                                const int* __restrict__ cols,
                                                const int* __restrict__ nnzArr,
                                                const float* __restrict__ dinv,
                                                float* __restrict__ part) {
  int row = blockIdx.x;
  int tid = threadIdx.x;
  int lane = tid & 63, wv = tid >> 6;
  __shared__ int scols[CAP];
  __shared__ float sdinv[CAP];
  __shared__ float sred[4][260];
  int nn = nnzArr[row];
  if (tid < nn) {
    int c = cols[(size_t)row * CAP + tid];
    scols[tid] = c;
    sdinv[tid] = dinv[c];
  }
  __syncthreads();
  float4 acc = make_float4(0.f, 0.f, 0.f, 0.f);
  for (int jj = wv; jj < nn; jj += 4) {
    uint2 u = *(const uint2*)(Houtb + (size_t)scols[jj] * DD + lane * 4);
    float w = sdinv[jj];
    acc.x += w * bflo(u.x); acc.y += w * bfhi(u.x);
    acc.z += w * bflo(u.y); acc.w += w * bfhi(u.y);
  }
  *(float4*)(&sred[wv][lane * 4]) = acc;
  __syncthreads();
  if (wv == 0) {
    float4 s4;
    s4.x = sred[0][lane * 4 + 0] + sred[1][lane * 4 + 0] + sred[2][lane * 4 + 0] + sred[3][lane * 4 + 0];
    s4.y = sred[0][lane * 4 + 1] + sred[1][lane * 4 + 1] + sred[2][lane * 4 + 1] + sred[3][lane * 4 + 1];
    s4.z = sred[0][lane * 4 + 2] + sred[1][lane * 4 + 2] + sred[2][lane * 4 + 2] + sred[3][lane * 4 + 2];
    s4.w = sred[0][lane * 4 + 3] + sred[1][lane * 4 + 3] + sred[2][lane * 4 + 3] + sred[3][lane * 4 + 3];
    float4 h4 = *(const float4*)(Hout + (size_t)row * DD + lane * 4);
    float dvr = dinv[row];
    float val = h4.x * (h4.x - dvr * s4.x) + h4.y * (h4.y - dvr * s4.y) +
                h4.z * (h4.z - dvr * s4.z) + h4.w * (h4.w - dvr * s4.w);
#pragma unroll
    for (int off = 32; off > 0; off >>= 1) val += __shfl_xor(val, off);
    if (lane == 0) part[row] = val;
  }
}

// ======== K6: deterministic final reduction ==============================================
__global__ __launch_bounds__(256) void finalize(const float* __restrict__ lap_part,
                                                const float* __restrict__ orth_part,
                                                float* __restrict__ out) {
  __shared__ double red[256];
  int tid = threadIdx.x;
  double s = 0.0;
  for (int i = tid; i < NN; i += 256) s += (double)lap_part[i];
  red[tid] = s;
  __syncthreads();
  for (int off = 128; off > 0; off >>= 1) {
    if (tid < off) red[tid] += red[tid + off];
    __syncthreads();
  }
  if (tid == 0) {
    double o = 0.0;
    for (int i = 0; i < 10; ++i) o += (double)orth_part[i];
    out[(size_t)NN * DD] = (float)o;
    out[(size_t)NN * DD + 1] = (float)red[0];
  }
}

extern "C" void kernel_launch(void* const* d_in, const int* in_sizes, int n_in,
                              void* d_out, int out_size, void* d_ws, size_t ws_size,
                              hipStream_t stream) {
  const float* H = (const float*)d_in[0];
  const float* A = (const float*)d_in[1];
  // d_in[2] (dense L) intentionally unused: L reconstructed exactly from A.
  const float* U = (const float*)d_in[3];
  const float* lambda_p = (const float*)d_in[4];
  const float* thr = (const float*)d_in[5];
  float* out = (float*)d_out;

  char* w = (char*)d_ws;
  float* B2 = (float*)w;             w += (size_t)PP * DD * 4;     // 128 KB
  int* cols = (int*)w;               w += (size_t)NN * CAP * 4;    // 4 MB
  int* lowCols = (int*)w;            w += (size_t)NN * CAPL * 4;   // 4 MB
  int* upCols = (int*)w;             w += (size_t)NN * CAPL * 4;   // 4 MB
  int* lowCnt = (int*)w;             w += (size_t)NN * 4;
  int* upCnt = (int*)w;              w += (size_t)NN * 4;
  int* nnzArr = (int*)w;             w += (size_t)NN * 4;
  float* dinv = (float*)w;           w += (size_t)NN * 4;
  unsigned short* Zb = (unsigned short*)w;   w += (size_t)NN * PP * 2;   // 2 MB
  unsigned short* Hb = (unsigned short*)w;   w += (size_t)NN * DD * 2;   // 4 MB
  unsigned short* Houtb = (unsigned short*)w; w += (size_t)NN * DD * 2;  // 4 MB
  float* aggZ = (float*)w;           w += (size_t)NN * PP * 4;     // 4 MB
  float* S = (float*)w;              w += (size_t)NN * DD * 4;     // 8 MB
  float* lap_part = (float*)w;       w += (size_t)NN * 4;
  float* orth_part = (float*)w;      w += 64;

  hipMemsetAsync(upCnt, 0, (size_t)NN * 4, stream);   // graph-capturable
  zgemm_scan<<<dim3(650 + NN), dim3(256), 0, stream>>>(A, H, U, B2, Zb, Hb, orth_part,
                                                       lowCols, lowCnt, upCols, upCnt);
  csr_attn<<<dim3(NN), dim3(256), 0, stream>>>(Zb, lowCols, lowCnt, upCols, upCnt,
                                               cols, nnzArr, dinv, aggZ);
  sgather<<<dim3(NN), dim3(256), 0, stream>>>(Hb, cols, nnzArr, dinv, S);
  egemm<<<dim3(NN / 32, 2), dim3(256), 0, stream>>>(aggZ, B2, H, S, dinv, thr, lambda_p,
                                                    out, Houtb);
  lap_rows<<<dim3(NN), dim3(256), 0, stream>>>(out, Houtb, cols, nnzArr, dinv, lap_part);
  finalize<<<dim3(1), dim3(256), 0, stream>>>(lap_part, orth_part, out);
}

// Round 10
// 152.616 us; speedup vs baseline: 2.7974x; 1.0480x over previous
//
#include <hip/hip_runtime.h>
#include <hip/hip_bf16.h>
#include <math.h>

#define NN 8192
#define DD 256
#define RR 32
#define KH 4
#define PP 128      // KH*RR
#define CAP 128     // max neighbors per row (mean ~34)
#define CAPL 128    // per-row capacity of lower/upper half-lists
#define NSTASH 48   // neighbors stashed in LDS (P(nn>48) ~ 0.6%; global fallback)
#define ETA 0.5f
#define SCALE 0.17677669529663687f  // 1/sqrt(32)

// bf16 helpers (explicit bit ops: deterministic)
__device__ __forceinline__ unsigned short f2bf(float f) {
  union { float f; unsigned u; } v; v.f = f;
  unsigned r = v.u + 0x7fffu + ((v.u >> 16) & 1u);   // round-to-nearest-even
  return (unsigned short)(r >> 16);
}
__device__ __forceinline__ float bflo(unsigned u) { return __uint_as_float(u << 16); }
__device__ __forceinline__ float bfhi(unsigned u) { return __uint_as_float(u & 0xffff0000u); }

// ======== K1: Z-GEMM (0..255) | orth (256..265) | B2 (266..393) | Hb (394..649)
//              | symmetric lower-triangle A-scan (650..8841) ==============================
__global__ __launch_bounds__(256) void zgemm_scan(const float* __restrict__ A,
                                                  const float* __restrict__ H,
                                                  const float* __restrict__ U,
                                                  float* __restrict__ B2,
                                                  unsigned short* __restrict__ Zb,
                                                  unsigned short* __restrict__ Hb,
                                                  float* __restrict__ orth_part,
                                                  int* __restrict__ lowCols,
                                                  int* __restrict__ lowCnt,
                                                  int* __restrict__ upCols,
                                                  int* __restrict__ upCnt) {
  __shared__ float smem[5152];
  int tid = threadIdx.x;
  int bx = blockIdx.x;
  int lane = tid & 63, wv = tid >> 6;

  if (bx >= 650) {
    // ---- symmetric scan: strict-lower triangle only (134 MB total) ----
    int row = (NN - 1) - (bx - 650);   // longest scans dispatch first
    const float* a = A + (size_t)row * NN;
    __shared__ int wsum2[4];
    __shared__ int sbase;
    if (tid == 0) sbase = 0;
    int nch = (row >> 10) + 1;
    for (int c = 0; c < nch; ++c) {
      int g0 = c * 1024 + tid * 4;
      float4 x = *(const float4*)(a + g0);
      int m0 = (g0 + 0 < row) && (x.x != 0.f);
      int m1 = (g0 + 1 < row) && (x.y != 0.f);
      int m2 = (g0 + 2 < row) && (x.z != 0.f);
      int m3 = (g0 + 3 < row) && (x.w != 0.f);
      int cnt = m0 + m1 + m2 + m3;
      int incl = cnt;
#pragma unroll
      for (int off = 1; off < 64; off <<= 1) {
        int t = __shfl_up(incl, off);
        if (lane >= off) incl += t;
      }
      if (lane == 63) wsum2[wv] = incl;
      __syncthreads();
      int base = sbase;
#pragma unroll
      for (int w = 0; w < 4; ++w) if (w < wv) base += wsum2[w];
      int o = base + incl - cnt;
      int chunkTot = wsum2[0] + wsum2[1] + wsum2[2] + wsum2[3];
      if (m0) { int col = g0 + 0; if (o < CAPL) { lowCols[(size_t)row * CAPL + o] = col; int s = atomicAdd(&upCnt[col], 1); if (s < CAPL) upCols[(size_t)col * CAPL + s] = row; } o++; }
      if (m1) { int col = g0 + 1; if (o < CAPL) { lowCols[(size_t)row * CAPL + o] = col; int s = atomicAdd(&upCnt[col], 1); if (s < CAPL) upCols[(size_t)col * CAPL + s] = row; } o++; }
      if (m2) { int col = g0 + 2; if (o < CAPL) { lowCols[(size_t)row * CAPL + o] = col; int s = atomicAdd(&upCnt[col], 1); if (s < CAPL) upCols[(size_t)col * CAPL + s] = row; } o++; }
      if (m3) { int col = g0 + 3; if (o < CAPL) { lowCols[(size_t)row * CAPL + o] = col; int s = atomicAdd(&upCnt[col], 1); if (s < CAPL) upCols[(size_t)col * CAPL + s] = row; } o++; }
      __syncthreads();
      if (tid == 0) sbase = base + chunkTot;
    }
    __syncthreads();
    if (tid == 0) lowCnt[row] = sbase;
    return;
  }
  if (bx >= 394) {
    // ---- Hb: bf16 mirror of H ----
    int base = (bx - 394) * 8192;
#pragma unroll
    for (int q = 0; q < 8; ++q) {
      int idx = base + q * 1024 + tid * 4;
      float4 v = *(const float4*)(H + idx);
      uint2 p;
      p.x = (unsigned)f2bf(v.x) | ((unsigned)f2bf(v.y) << 16);
      p.y = (unsigned)f2bf(v.z) | ((unsigned)f2bf(v.w) << 16);
      *(uint2*)(Hb + idx) = p;
    }
    return;
  }
  if (bx >= 266) {
    // ---- B2 transpose ----
    int idx = (bx - 266) * 256 + tid;
    int k = idx / (DD * RR);
    int rem = idx % (DD * RR);
    int d = rem / RR;
    int r = rem % RR;
    B2[(k * RR + r) * DD + d] = U[idx];
    return;
  }
  if (bx >= 256) {
    // ---- orth ----
    int bid = bx - 256;
    int b = bid, k = 0;
    while (b >= (KH - k)) { b -= (KH - k); k++; }
    int l = k + b;
    float* redo = smem;
    const float* uk = U + (size_t)k * DD * RR;
    const float* ul = U + (size_t)l * DD * RR;
    float acc = 0.f;
#pragma unroll
    for (int q = 0; q < 4; ++q) {
      int e = tid * 4 + q;
      int r = e >> 5, s2 = e & 31;
      float g = 0.f;
      for (int d = 0; d < DD; ++d) g += uk[d * RR + r] * ul[d * RR + s2];
      if (k == l) {
        float c3 = g - (r == s2 ? 1.f : 0.f);
        acc += c3 * c3;
      } else {
        acc += g * g;
      }
    }
    redo[tid] = acc;
    __syncthreads();
    for (int off = 128; off > 0; off >>= 1) {
      if (tid < off) redo[tid] += redo[tid + off];
      __syncthreads();
    }
    if (tid == 0) orth_part[bid] = redo[0];
    return;
  }
  // ---- Z-GEMM: Zb = bf16(H @ B1) ----
  float* As = smem;
  float* Bs = smem + 1056;
  int r0 = bx * 32;
  int tx = tid & 15, ty = tid >> 4;
  int cx = tx * 8, ry = ty * 2;
  float acc[2][8];
#pragma unroll
  for (int i = 0; i < 2; ++i)
#pragma unroll
    for (int j = 0; j < 8; ++j) acc[i][j] = 0.f;

  for (int k0 = 0; k0 < DD; k0 += 32) {
    {
      int r = tid >> 3;
      int kc = (tid & 7) * 4;
      float4 x = *(const float4*)(H + (size_t)(r0 + r) * DD + k0 + kc);
      As[(kc + 0) * 33 + r] = x.x; As[(kc + 1) * 33 + r] = x.y;
      As[(kc + 2) * 33 + r] = x.z; As[(kc + 3) * 33 + r] = x.w;
    }
#pragma unroll
    for (int q = 0; q < 4; ++q) {
      int f = tid + 256 * q;
      int kk = f >> 5, pc = (f & 31) * 4;
      *(float4*)(&Bs[kk * 128 + pc]) =
          *(const float4*)(U + (size_t)(pc >> 5) * DD * RR + (size_t)(k0 + kk) * RR + (pc & 31));
    }
    __syncthreads();
#pragma unroll
    for (int kk = 0; kk < 32; ++kk) {
      float av[2];
      av[0] = As[kk * 33 + ry]; av[1] = As[kk * 33 + ry + 1];
      float bv[8];
      *(float4*)(bv) = *(const float4*)(&Bs[kk * 128 + cx]);
      *(float4*)(bv + 4) = *(const float4*)(&Bs[kk * 128 + cx + 4]);
#pragma unroll
      for (int i = 0; i < 2; ++i)
#pragma unroll
        for (int j = 0; j < 8; ++j) acc[i][j] += av[i] * bv[j];
    }
    __syncthreads();
  }
#pragma unroll
  for (int i = 0; i < 2; ++i) {
    uint4 p;
    p.x = (unsigned)f2bf(acc[i][0]) | ((unsigned)f2bf(acc[i][1]) << 16);
    p.y = (unsigned)f2bf(acc[i][2]) | ((unsigned)f2bf(acc[i][3]) << 16);
    p.z = (unsigned)f2bf(acc[i][4]) | ((unsigned)f2bf(acc[i][5]) << 16);
    p.w = (unsigned)f2bf(acc[i][6]) | ((unsigned)f2bf(acc[i][7]) << 16);
    *(uint4*)(Zb + (size_t)(r0 + ry + i) * PP + cx) = p;
  }
}

// ======== K2: assemble CSR -> S-gather + attention (merged; ~18.7 KB LDS, 8 blk/CU) ======
__global__ __launch_bounds__(256) void csr_attn_s(const unsigned short* __restrict__ Zb,
                                                  const unsigned short* __restrict__ Hb,
                                                  const int* __restrict__ lowCols,
                                                  const int* __restrict__ lowCnt,
                                                  const int* __restrict__ upCols,
                                                  const int* __restrict__ upCnt,
                                                  float* __restrict__ dinv,
                                                  float* __restrict__ aggZ,
                                                  float* __restrict__ S) {
  int row = blockIdx.x;
  int tid = threadIdx.x;
  int lane = tid & 63, wv = tid >> 6;
  __shared__ int scols[CAP];
  __shared__ int utmp[CAPL];
  __shared__ float zi[PP];
  __shared__ unsigned short zzb[NSTASH][130];  // stride 65 words: conflict-free
  __shared__ float sdinv[CAP];
  __shared__ float uni[1024];  // union: sred f4[4][64] | alpha[4][128]+redp f2[4][64]

  // own Z row (bf16 -> f32)
  if (tid < PP) zi[tid] = bflo((unsigned)Zb[(size_t)row * PP + tid]);

  // ---- assemble neighbor list: lower ++ diag ++ rank-sorted upper (== dense-scan order) --
  int lcT = lowCnt[row];
  int ucT = upCnt[row];
  int lc = lcT < (CAP - 1) ? lcT : (CAP - 1);
  for (int t = tid; t < lc; t += 256) scols[t] = lowCols[(size_t)row * CAPL + t];
  if (tid == 0) scols[lc] = row;
  int ucR = ucT < CAPL ? ucT : CAPL;
  for (int t = tid; t < ucR; t += 256) utmp[t] = upCols[(size_t)row * CAPL + t];
  __syncthreads();
  for (int t = tid; t < ucR; t += 256) {
    int e = utmp[t], r = 0;
    for (int q = 0; q < ucR; ++q) r += (utmp[q] < e);   // distinct -> exact rank
    int pos = lc + 1 + r;
    if (pos < CAP) scols[pos] = e;
  }
  int total = lcT + 1 + ucT;
  int nn = total < CAP ? total : CAP;
  if (tid == 0) dinv[row] = 1.0f / sqrtf((float)total);
  __syncthreads();

  // per-neighbor dinv on the fly (lowCnt/upCnt are L2-hot 32KB arrays)
  if (tid < nn) {
    int c = scols[tid];
    int cc = lowCnt[c] + 1 + upCnt[c];
    sdinv[tid] = 1.0f / sqrtf((float)cc);
  }
  __syncthreads();

  // ---- combined loop: Zb stash (jj<NSTASH) + S gather over Hb, two streams ----
  {
    float4 acc = make_float4(0.f, 0.f, 0.f, 0.f);
    for (int jj = wv; jj < nn; jj += 4) {
      int c = scols[jj];
      if (jj < NSTASH) {
        unsigned x = *(const unsigned*)(Zb + (size_t)c * PP + lane * 2);
        *(unsigned*)(&zzb[jj][lane * 2]) = x;
      }
      uint2 u = *(const uint2*)(Hb + (size_t)c * DD + lane * 4);
      float w = sdinv[jj];
      acc.x += w * bflo(u.x); acc.y += w * bfhi(u.x);
      acc.z += w * bflo(u.y); acc.w += w * bfhi(u.y);
    }
    *(float4*)(&uni[wv * 256 + lane * 4]) = acc;   // sred[wv][lane]
  }
  __syncthreads();
  {
    float s = uni[0 * 256 + tid] + uni[1 * 256 + tid] + uni[2 * 256 + tid] + uni[3 * 256 + tid];
    S[(size_t)row * DD + tid] = s;
  }
  __syncthreads();   // sred dead; uni becomes alpha/redp

  // ---- scores + wave-parallel softmax (wave wv = head wv) ----
  {
    int k = wv;
    float s0 = -1e30f, s1 = -1e30f;
    if (lane < nn) {
      float acc = 0.f;
      if (lane < NSTASH) {
        const unsigned short* zs = &zzb[lane][k * RR];
#pragma unroll
        for (int r = 0; r < RR; r += 4) {
          float4 aa = *(const float4*)(zi + k * RR + r);
          unsigned u0 = *(const unsigned*)(zs + r);
          unsigned u1 = *(const unsigned*)(zs + r + 2);
          acc += aa.x * bflo(u0) + aa.y * bfhi(u0) + aa.z * bflo(u1) + aa.w * bfhi(u1);
        }
      } else {
        const unsigned short* zj = Zb + (size_t)scols[lane] * PP + k * RR;
#pragma unroll
        for (int r = 0; r < RR; r += 4) {
          float4 aa = *(const float4*)(zi + k * RR + r);
          unsigned u0 = *(const unsigned*)(zj + r);
          unsigned u1 = *(const unsigned*)(zj + r + 2);
          acc += aa.x * bflo(u0) + aa.y * bfhi(u0) + aa.z * bflo(u1) + aa.w * bfhi(u1);
        }
      }
      s0 = acc * SCALE;
    }
    int j1 = lane + 64;
    if (j1 < nn) {
      const unsigned short* zj = Zb + (size_t)scols[j1] * PP + k * RR;
      float acc = 0.f;
#pragma unroll
      for (int r = 0; r < RR; r += 4) {
        float4 aa = *(const float4*)(zi + k * RR + r);
        unsigned u0 = *(const unsigned*)(zj + r);
        unsigned u1 = *(const unsigned*)(zj + r + 2);
        acc += aa.x * bflo(u0) + aa.y * bfhi(u0) + aa.z * bflo(u1) + aa.w * bfhi(u1);
      }
      s1 = acc * SCALE;
    }
    float m = fmaxf(s0, s1);
#pragma unroll
    for (int off = 32; off > 0; off >>= 1) m = fmaxf(m, __shfl_xor(m, off));
    float e0 = (lane < nn) ? expf(s0 - m) : 0.f;
    float e1 = (j1 < nn) ? expf(s1 - m) : 0.f;
    float s = e0 + e1;
#pragma unroll
    for (int off = 32; off > 0; off >>= 1) s += __shfl_xor(s, off);
    float inv = 1.0f / s;
    if (lane < nn) uni[k * CAP + lane] = e0 * inv;        // alpha[k][lane]
    if (j1 < nn) uni[k * CAP + j1] = e1 * inv;
  }
  __syncthreads();

  // ---- aggZ = sum_j alpha*zz; thread owns col-pair, 4-way jj split ----
  {
    int c2 = tid & 63, hf = tid >> 6;
    int hd = c2 >> 4;
    float a0 = 0.f, a1 = 0.f;
    for (int jj = hf; jj < nn; jj += 4) {
      unsigned u;
      if (jj < NSTASH) u = *(const unsigned*)(&zzb[jj][c2 * 2]);
      else u = *(const unsigned*)(Zb + (size_t)scols[jj] * PP + c2 * 2);
      float al = uni[hd * CAP + jj];
      a0 += al * bflo(u);
      a1 += al * bfhi(u);
    }
    *(float2*)(&uni[512 + hf * 128 + c2 * 2]) = make_float2(a0, a1);   // redp[hf][c2]
  }
  __syncthreads();
  if (tid < 64) {
    float2 r0 = *(float2*)(&uni[512 + 0 * 128 + tid * 2]);
    float2 r1 = *(float2*)(&uni[512 + 1 * 128 + tid * 2]);
    float2 r2 = *(float2*)(&uni[512 + 2 * 128 + tid * 2]);
    float2 r3 = *(float2*)(&uni[512 + 3 * 128 + tid * 2]);
    float2 s2 = make_float2(r0.x + r1.x + r2.x + r3.x, r0.y + r1.y + r2.y + r3.y);
    *(float2*)(aggZ + (size_t)row * PP + tid * 2) = s2;
  }
}

// ======== K3: epilogue GEMM + Laplacian + soft-threshold; writes out f32 + Houtb bf16 =====
__global__ __launch_bounds__(256) void egemm(const float* __restrict__ A,   // aggZ [N][128]
                                             const float* __restrict__ B,   // B2 [128][256]
                                             const float* __restrict__ Hm,
                                             const float* __restrict__ S,
                                             const float* __restrict__ dinv,
                                             const float* __restrict__ thr,
                                             const float* __restrict__ lambda_p,
                                             float* __restrict__ out,
                                             unsigned short* __restrict__ Houtb) {
  __shared__ float As[32][33];
  __shared__ float Bs[32][128];
  int tid = threadIdx.x;
  int r0 = blockIdx.x * 32;
  int c0 = blockIdx.y * 128;
  int tx = tid & 15, ty = tid >> 4;
  int cx = tx * 8, ry = ty * 2;
  float acc[2][8];
#pragma unroll
  for (int i = 0; i < 2; ++i)
#pragma unroll
    for (int j = 0; j < 8; ++j) acc[i][j] = 0.f;

  for (int k0 = 0; k0 < PP; k0 += 32) {
    {
      int r = tid >> 3;
      int kc = (tid & 7) * 4;
      float4 x = *(const float4*)(A + (size_t)(r0 + r) * PP + k0 + kc);
      As[kc + 0][r] = x.x; As[kc + 1][r] = x.y; As[kc + 2][r] = x.z; As[kc + 3][r] = x.w;
    }
#pragma unroll
    for (int q = 0; q < 4; ++q) {
      int f = tid + 256 * q;
      int kk = f >> 5, pc = (f & 31) * 4;
      *(float4*)(&Bs[kk][pc]) = *(const float4*)(B + (size_t)(k0 + kk) * DD + c0 + pc);
    }
    __syncthreads();
#pragma unroll
    for (int kk = 0; kk < 32; ++kk) {
      float av[2];
      av[0] = As[kk][ry]; av[1] = As[kk][ry + 1];
      float bv[8];
      *(float4*)(bv) = *(const float4*)(&Bs[kk][cx]);
      *(float4*)(bv + 4) = *(const float4*)(&Bs[kk][cx + 4]);
#pragma unroll
      for (int i = 0; i < 2; ++i)
#pragma unroll
        for (int j = 0; j < 8; ++j) acc[i][j] += av[i] * bv[j];
    }
    __syncthreads();
  }
  float lam = lambda_p[0];
  int gc = c0 + cx;
  float4 t0 = *(const float4*)(thr + gc);
  float4 t1 = *(const float4*)(thr + gc + 4);
#pragma unroll
  for (int i = 0; i < 2; ++i) {
    int gr = r0 + ry + i;
    float dv = dinv[gr];
    float4 h0 = *(const float4*)(Hm + (size_t)gr * DD + gc);
    float4 h1 = *(const float4*)(Hm + (size_t)gr * DD + gc + 4);
    float4 s0 = *(const float4*)(S + (size_t)gr * DD + gc);
    float4 s1 = *(const float4*)(S + (size_t)gr * DD + gc + 4);
    float hv[8] = {h0.x, h0.y, h0.z, h0.w, h1.x, h1.y, h1.z, h1.w};
    float sv[8] = {s0.x, s0.y, s0.z, s0.w, s1.x, s1.y, s1.z, s1.w};
    float tv[8] = {t0.x, t0.y, t0.z, t0.w, t1.x, t1.y, t1.z, t1.w};
    float ov[8];
#pragma unroll
    for (int j = 0; j < 8; ++j) {
      float val = hv[j] + ETA * acc[i][j] - ETA * lam * (hv[j] - dv * sv[j]);
      float av = fabsf(val) - tv[j];
      ov[j] = (av > 0.f) ? copysignf(av, val) : 0.f;
    }
    *(float4*)(out + (size_t)gr * DD + gc) = make_float4(ov[0], ov[1], ov[2], ov[3]);
    *(float4*)(out + (size_t)gr * DD + gc + 4) = make_float4(ov[4], ov[5], ov[6], ov[7]);
    uint4 p;
    p.x = (unsigned)f2bf(ov[0]) | ((unsigned)f2bf(ov[1]) << 16);
    p.y = (unsigned)f2bf(ov[2]) | ((unsigned)f2bf(ov[3]) << 16);
    p.z = (unsigned)f2bf(ov[4]) | ((unsigned)f2bf(ov[5]) << 16);
    p.w = (unsigned)f2bf(ov[6]) | ((unsigned)f2bf(ov[7]) << 16);
    *(uint4*)(Houtb + (size_t)gr * DD + gc) = p;
  }
}

// ======== K4: lap_smooth via lower edges only (halved gather traffic) =====================
// lap = sum_i ||h_i||^2 (1 - dinv_i^2) - sum_{lower edges (i,j)} 2 dinv_i dinv_j <h_i,h_j>
__global__ __launch_bounds__(256) void lap_rows(const float* __restrict__ Hout,
                                                const unsigned short* __restrict__ Houtb,
                                                const int* __restrict__ lowCols,
                                                const int* __restrict__ lowCnt,
                                                const float* __restrict__ dinv,
                                                float* __restrict__ part) {
  int row = (NN - 1) - blockIdx.x;   // heavy rows first
  int tid = threadIdx.x;
  int lane = tid & 63, wv = tid >> 6;
  __shared__ int scols[CAPL];
  __shared__ float sdinv[CAPL];
  __shared__ float sred[4][260];
  int lcT = lowCnt[row];
  int lc = lcT < CAPL ? lcT : CAPL;
  if (tid < lc) {
    int c = lowCols[(size_t)row * CAPL + tid];
    scols[tid] = c;
    sdinv[tid] = 2.0f * dinv[c];
  }
  __syncthreads();
  float4 acc = make_float4(0.f, 0.f, 0.f, 0.f);
  for (int jj = wv; jj < lc; jj += 4) {
    uint2 u = *(const uint2*)(Houtb + (size_t)scols[jj] * DD + lane * 4);
    float w = sdinv[jj];
    acc.x += w * bflo(u.x); acc.y += w * bfhi(u.x);
    acc.z += w * bflo(u.y); acc.w += w * bfhi(u.y);
  }
  *(float4*)(&sred[wv][lane * 4]) = acc;
  __syncthreads();
  if (wv == 0) {
    float4 s4;
    s4.x = sred[0][lane * 4 + 0] + sred[1][lane * 4 + 0] + sred[2][lane * 4 + 0] + sred[3][lane * 4 + 0];
    s4.y = sred[0][lane * 4 + 1] + sred[1][lane * 4 + 1] + sred[2][lane * 4 + 1] + sred[3][lane * 4 + 1];
    s4.z = sred[0][lane * 4 + 2] + sred[1][lane * 4 + 2] + sred[2][lane * 4 + 2] + sred[3][lane * 4 + 2];
    s4.w = sred[0][lane * 4 + 3] + sred[1][lane * 4 + 3] + sred[2][lane * 4 + 3] + sred[3][lane * 4 + 3];
    float4 h4 = *(const float4*)(Hout + (size_t)row * DD + lane * 4);
    float dvr = dinv[row];
    float own = 1.0f - dvr * dvr;
    float val = h4.x * (own * h4.x - dvr * s4.x) + h4.y * (own * h4.y - dvr * s4.y) +
                h4.z * (own * h4.z - dvr * s4.z) + h4.w * (own * h4.w - dvr * s4.w);
#pragma unroll
    for (int off = 32; off > 0; off >>= 1) val += __shfl_xor(val, off);
    if (lane == 0) part[row] = val;
  }
}

// ======== K5: deterministic final reduction ==============================================
__global__ __launch_bounds__(256) void finalize(const float* __restrict__ lap_part,
                                                const float* __restrict__ orth_part,
                                                float* __restrict__ out) {
  __shared__ double red[256];
  int tid = threadIdx.x;
  double s = 0.0;
  for (int i = tid; i < NN; i += 256) s += (double)lap_part[i];
  red[tid] = s;
  __syncthreads();
  for (int off = 128; off > 0; off >>= 1) {
    if (tid < off) red[tid] += red[tid + off];
    __syncthreads();
  }
  if (tid == 0) {
    double o = 0.0;
    for (int i = 0; i < 10; ++i) o += (double)orth_part[i];
    out[(size_t)NN * DD] = (float)o;
    out[(size_t)NN * DD + 1] = (float)red[0];
  }
}

extern "C" void kernel_launch(void* const* d_in, const int* in_sizes, int n_in,
                              void* d_out, int out_size, void* d_ws, size_t ws_size,
                              hipStream_t stream) {
  const float* H = (const float*)d_in[0];
  const float* A = (const float*)d_in[1];
  // d_in[2] (dense L) intentionally unused: L reconstructed exactly from A.
  const float* U = (const float*)d_in[3];
  const float* lambda_p = (const float*)d_in[4];
  const float* thr = (const float*)d_in[5];
  float* out = (float*)d_out;

  char* w = (char*)d_ws;
  float* B2 = (float*)w;             w += (size_t)PP * DD * 4;     // 128 KB
  int* lowCols = (int*)w;            w += (size_t)NN * CAPL * 4;   // 4 MB
  int* upCols = (int*)w;             w += (size_t)NN * CAPL * 4;   // 4 MB
  int* lowCnt = (int*)w;             w += (size_t)NN * 4;
  int* upCnt = (int*)w;              w += (size_t)NN * 4;
  float* dinv = (float*)w;           w += (size_t)NN * 4;
  unsigned short* Zb = (unsigned short*)w;   w += (size_t)NN * PP * 2;   // 2 MB
  unsigned short* Hb = (unsigned short*)w;   w += (size_t)NN * DD * 2;   // 4 MB
  unsigned short* Houtb = (unsigned short*)w; w += (size_t)NN * DD * 2;  // 4 MB
  float* aggZ = (float*)w;           w += (size_t)NN * PP * 4;     // 4 MB
  float* S = (float*)w;              w += (size_t)NN * DD * 4;     // 8 MB
  float* lap_part = (float*)w;       w += (size_t)NN * 4;
  float* orth_part = (float*)w;      w += 64;

  hipMemsetAsync(upCnt, 0, (size_t)NN * 4, stream);   // graph-capturable
  zgemm_scan<<<dim3(650 + NN), dim3(256), 0, stream>>>(A, H, U, B2, Zb, Hb, orth_part,
                                                       lowCols, lowCnt, upCols, upCnt);
  csr_attn_s<<<dim3(NN), dim3(256), 0, stream>>>(Zb, Hb, lowCols, lowCnt, upCols, upCnt,
                                                 dinv, aggZ, S);
  egemm<<<dim3(NN / 32, 2), dim3(256), 0, stream>>>(aggZ, B2, H, S, dinv, thr, lambda_p,
                                                    out, Houtb);
  lap_rows<<<dim3(NN), dim3(256), 0, stream>>>(out, Houtb, lowCols, lowCnt, dinv, lap_part);
  finalize<<<dim3(1), dim3(256), 0, stream>>>(lap_part, orth_part, out);
}